// Round 2
// baseline (620.685 us; speedup 1.0000x reference)
//
#include <hip/hip_runtime.h>

#define NEG_SLOPE 0.2f
#define EPSF 1e-16f

// ------- GEMM1: xh1 = x @ W1 (N x 128)(128 x 128), fused e_src1/e_dst1 --------
__global__ __launch_bounds__(256) void k_gemm1(const float* __restrict__ x,
                                               const float* __restrict__ W,
                                               const float* __restrict__ asrc,
                                               const float* __restrict__ adst,
                                               float* __restrict__ xh,
                                               float* __restrict__ es,
                                               float* __restrict__ ed, int N) {
    __shared__ float xs[32][132];   // 32 rows x 128, padded stride 132
    __shared__ float wsh[32][128];  // one 32-row k-panel of W
    const int t = threadIdx.x;
    const int row0 = blockIdx.x * 32;

    // stage x tile (32 x 128) as float4
    for (int i = t; i < 32 * 32; i += 256) {
        int r = i >> 5, c4 = i & 31;
        float4 v = make_float4(0.f, 0.f, 0.f, 0.f);
        if (row0 + r < N) v = ((const float4*)(x + (size_t)(row0 + r) * 128))[c4];
        *(float4*)&xs[r][c4 * 4] = v;
    }

    const int r0 = (t >> 5) * 4;   // 8 row-groups of 4
    const int c0 = (t & 31) * 4;   // 32 col-groups of 4
    float acc[4][4] = {};

    for (int kp = 0; kp < 128; kp += 32) {
        __syncthreads();           // x tile ready / previous panel consumed
        for (int i = t; i < 32 * 32; i += 256) {
            int kr = i >> 5, c4 = i & 31;
            ((float4*)&wsh[kr][0])[c4] =
                ((const float4*)(W + (size_t)(kp + kr) * 128))[c4];
        }
        __syncthreads();
        #pragma unroll
        for (int kk = 0; kk < 32; ++kk) {
            const float4 wv = *(const float4*)&wsh[kk][c0];
            const int k = kp + kk;
            #pragma unroll
            for (int i = 0; i < 4; ++i) {
                const float xv = xs[r0 + i][k];
                acc[i][0] += xv * wv.x;
                acc[i][1] += xv * wv.y;
                acc[i][2] += xv * wv.z;
                acc[i][3] += xv * wv.w;
            }
        }
    }

    // write xh tile
    #pragma unroll
    for (int i = 0; i < 4; ++i) {
        const int row = row0 + r0 + i;
        if (row < N) {
            *(float4*)(xh + (size_t)row * 128 + c0) =
                make_float4(acc[i][0], acc[i][1], acc[i][2], acc[i][3]);
        }
    }

    // fused e_src/e_dst: head = c0>>4, this thread's 4 cols live in one head
    const int head = c0 >> 4;
    const int cb   = c0 & 15;
    float4 av = *(const float4*)(asrc + head * 16 + cb);
    float4 bv = *(const float4*)(adst + head * 16 + cb);
    #pragma unroll
    for (int i = 0; i < 4; ++i) {
        float ps = acc[i][0] * av.x + acc[i][1] * av.y + acc[i][2] * av.z + acc[i][3] * av.w;
        float pd = acc[i][0] * bv.x + acc[i][1] * bv.y + acc[i][2] * bv.z + acc[i][3] * bv.w;
        ps += __shfl_xor(ps, 1, 64); ps += __shfl_xor(ps, 2, 64);
        pd += __shfl_xor(pd, 1, 64); pd += __shfl_xor(pd, 2, 64);
        const int row = row0 + r0 + i;
        if ((t & 3) == 0 && row < N) {
            es[row * 8 + head] = ps;
            ed[row * 8 + head] = pd;
        }
    }
}

// ------------------------- CSR build: histogram by dst -------------------------
__global__ void k_hist(const int* __restrict__ ei, int E, int N, int* __restrict__ deg) {
    const int Et = E + N;
    for (int e = blockIdx.x * blockDim.x + threadIdx.x; e < Et;
         e += gridDim.x * blockDim.x) {
        int d = (e < E) ? ei[E + e] : (e - E);   // self-loop tail
        atomicAdd(&deg[d], 1);
    }
}

__global__ __launch_bounds__(256) void k_scan_a(const int* __restrict__ deg,
                                                int* __restrict__ rowp,
                                                int* __restrict__ bsum, int N) {
    __shared__ int sd[256];
    const int t = threadIdx.x;
    const int i = blockIdx.x * 256 + t;
    const int v = (i < N) ? deg[i] : 0;
    sd[t] = v;
    __syncthreads();
    for (int off = 1; off < 256; off <<= 1) {
        int add = (t >= off) ? sd[t - off] : 0;
        __syncthreads();
        sd[t] += add;
        __syncthreads();
    }
    if (i < N) rowp[i] = sd[t] - v;              // exclusive within block
    if (t == 255) bsum[blockIdx.x] = sd[255];
}

__global__ __launch_bounds__(512) void k_scan_b(int* __restrict__ bsum, int NB) {
    __shared__ int sd[512];
    const int t = threadIdx.x;
    const int v = (t < NB) ? bsum[t] : 0;
    sd[t] = v;
    __syncthreads();
    for (int off = 1; off < 512; off <<= 1) {
        int add = (t >= off) ? sd[t - off] : 0;
        __syncthreads();
        sd[t] += add;
        __syncthreads();
    }
    if (t < NB) bsum[t] = sd[t] - v;             // exclusive block bases
}

__global__ __launch_bounds__(256) void k_scan_c(int* __restrict__ rowp,
                                                const int* __restrict__ bsum,
                                                int* __restrict__ fill, int N) {
    const int i = blockIdx.x * 256 + threadIdx.x;
    if (i >= N) return;
    const int v = rowp[i] + bsum[blockIdx.x];
    rowp[i] = v;
    fill[i] = v;
}

__global__ void k_scatter(const int* __restrict__ ei, int E, int N,
                          int* __restrict__ fill, int* __restrict__ csr) {
    const int Et = E + N;
    for (int e = blockIdx.x * blockDim.x + threadIdx.x; e < Et;
         e += gridDim.x * blockDim.x) {
        int s, d;
        if (e < E) { s = ei[e]; d = ei[E + e]; }
        else       { s = e - E; d = e - E; }
        const int pos = atomicAdd(&fill[d], 1);
        csr[pos] = s;
    }
}

// -------- layer-1 aggregate: one wave per dst node, 2 channels per lane --------
// Software-pipelined: csr prefetched 2 edges ahead, (es, xh) 1 edge ahead.
__global__ __launch_bounds__(256) void k_l1(const float* __restrict__ xh,
                                            const float* __restrict__ es,
                                            const float* __restrict__ ed,
                                            const int* __restrict__ rowp,
                                            const int* __restrict__ deg,
                                            const int* __restrict__ csr,
                                            const float* __restrict__ b1,
                                            float* __restrict__ hout, int N) {
    const int wave = threadIdx.x >> 6;
    const int lane = threadIdx.x & 63;
    const int n = blockIdx.x * 4 + wave;
    if (n >= N) return;
    const int h = lane >> 3;                     // channels 2*lane, 2*lane+1 -> head
    const float edv = ed[n * 8 + h];
    const int start = rowp[n];
    const int cnt = deg[n];

    float acc0 = 0.f, acc1 = 0.f, dsum = 0.f;
    if (cnt > 0) {
        const int last = cnt - 1;
        int sA = csr[start];                          // edge 0
        int sB = csr[start + min(1, last)];           // edge 1
        float esA = es[sA * 8 + h];
        float2 vA = *(const float2*)(xh + (size_t)sA * 128 + lane * 2);
        for (int k = 0; k < cnt; ++k) {
            const int sC = csr[start + min(k + 2, last)];
            const float esB = es[sB * 8 + h];
            const float2 vB = *(const float2*)(xh + (size_t)sB * 128 + lane * 2);
            float a = esA + edv;
            a = (a > 0.f) ? a : NEG_SLOPE * a;
            const float ea = __expf(a);
            acc0 += ea * vA.x;
            acc1 += ea * vA.y;
            dsum += ea;
            sB = sC; esA = esB; vA = vB;
        }
    }
    const float inv = 1.f / (dsum + EPSF);
    float o0 = acc0 * inv + b1[lane * 2];
    float o1 = acc1 * inv + b1[lane * 2 + 1];
    o0 = (o0 > 0.f) ? o0 : expm1f(o0);           // ELU
    o1 = (o1 > 0.f) ? o1 : expm1f(o1);
    *(float2*)(hout + (size_t)n * 128 + lane * 2) = make_float2(o0, o1);
}

// ------ GEMM2: xh2 = h @ W2 (N x 128)(128 x 40), fused e_src2/e_dst2 ---------
__global__ __launch_bounds__(256) void k_gemm2(const float* __restrict__ h,
                                               const float* __restrict__ W2,
                                               const float* __restrict__ as2,
                                               const float* __restrict__ ad2,
                                               float* __restrict__ xh2,
                                               float* __restrict__ es2,
                                               float* __restrict__ ed2, int N) {
    __shared__ float w[128 * 40];
    __shared__ float sa[40], sb[40];
    for (int i = threadIdx.x; i < 128 * 40 / 4; i += 256)
        ((float4*)w)[i] = ((const float4*)W2)[i];
    if (threadIdx.x < 40) { sa[threadIdx.x] = as2[threadIdx.x]; sb[threadIdx.x] = ad2[threadIdx.x]; }
    __syncthreads();
    const int n = blockIdx.x * 256 + threadIdx.x;
    if (n >= N) return;
    float acc[40];
    #pragma unroll
    for (int j = 0; j < 40; ++j) acc[j] = 0.f;
    const float4* hr = (const float4*)(h + (size_t)n * 128);
    for (int k4 = 0; k4 < 32; ++k4) {
        const float4 hv = hr[k4];
        const float hx[4] = {hv.x, hv.y, hv.z, hv.w};
        #pragma unroll
        for (int kk = 0; kk < 4; ++kk) {
            const float* wr = &w[(k4 * 4 + kk) * 40];
            #pragma unroll
            for (int j = 0; j < 40; j += 4) {
                const float4 wv = *(const float4*)&wr[j];
                acc[j]     += hx[kk] * wv.x;
                acc[j + 1] += hx[kk] * wv.y;
                acc[j + 2] += hx[kk] * wv.z;
                acc[j + 3] += hx[kk] * wv.w;
            }
        }
    }
    float4* op = (float4*)(xh2 + (size_t)n * 40);
    float s = 0.f, d = 0.f;
    #pragma unroll
    for (int j = 0; j < 10; ++j) {
        op[j] = make_float4(acc[4 * j], acc[4 * j + 1], acc[4 * j + 2], acc[4 * j + 3]);
        #pragma unroll
        for (int q = 0; q < 4; ++q) {
            s += acc[4 * j + q] * sa[4 * j + q];
            d += acc[4 * j + q] * sb[4 * j + q];
        }
    }
    es2[n] = s; ed2[n] = d;
}

// -------- layer-2 aggregate: one wave per dst node, lane = class channel --------
__global__ __launch_bounds__(256) void k_l2(const float* __restrict__ xh2,
                                            const float* __restrict__ es2,
                                            const float* __restrict__ ed2,
                                            const int* __restrict__ rowp,
                                            const int* __restrict__ deg,
                                            const int* __restrict__ csr,
                                            const float* __restrict__ b2,
                                            float* __restrict__ out, int N) {
    const int wave = threadIdx.x >> 6;
    const int lane = threadIdx.x & 63;
    const int n = blockIdx.x * 4 + wave;
    if (n >= N) return;
    const float edv = ed2[n];
    const int start = rowp[n];
    const int cnt = deg[n];
    float acc = 0.f, dsum = 0.f;
    if (cnt > 0) {
        const int last = cnt - 1;
        int sA = csr[start];
        int sB = csr[start + min(1, last)];
        float esA = es2[sA];
        float vA = (lane < 40) ? xh2[(size_t)sA * 40 + lane] : 0.f;
        for (int k = 0; k < cnt; ++k) {
            const int sC = csr[start + min(k + 2, last)];
            const float esB = es2[sB];
            const float vB = (lane < 40) ? xh2[(size_t)sB * 40 + lane] : 0.f;
            float a = esA + edv;
            a = (a > 0.f) ? a : NEG_SLOPE * a;
            const float ea = __expf(a);
            acc += ea * vA;
            dsum += ea;
            sB = sC; esA = esB; vA = vB;
        }
    }
    if (lane < 40)
        out[(size_t)n * 40 + lane] = acc / (dsum + EPSF) + b2[lane];
}

extern "C" void kernel_launch(void* const* d_in, const int* in_sizes, int n_in,
                              void* d_out, int out_size, void* d_ws, size_t ws_size,
                              hipStream_t stream) {
    const float* x   = (const float*)d_in[0];
    const int*   ei  = (const int*)d_in[1];
    const float* W1  = (const float*)d_in[2];
    const float* as1 = (const float*)d_in[3];
    const float* ad1 = (const float*)d_in[4];
    const float* b1  = (const float*)d_in[5];
    const float* W2  = (const float*)d_in[6];
    const float* as2 = (const float*)d_in[7];
    const float* ad2 = (const float*)d_in[8];
    const float* b2  = (const float*)d_in[9];
    float* out = (float*)d_out;

    const int N  = in_sizes[0] / 128;
    const int E  = in_sizes[1] / 2;
    const int Et = E + N;
    const int NB = (N + 255) / 256;   // 391 for N=100000 (fits the 512-wide scan_b)

    // ---- workspace layout (~117 MB) ----
    char* p = (char*)d_ws;
    float* xh1  = (float*)p; p += (size_t)N * 128 * 4;
    float* es1  = (float*)p; p += (size_t)N * 8 * 4;
    float* ed1  = (float*)p; p += (size_t)N * 8 * 4;
    int*   deg  = (int*)p;   p += (size_t)N * 4;
    int*   rowp = (int*)p;   p += (size_t)N * 4;
    int*   fill = (int*)p;   p += (size_t)N * 4;
    int*   bsum = (int*)p;   p += 2048 * 4;
    int*   csr  = (int*)p;   p += (size_t)Et * 4;
    float* hbuf = (float*)p; p += (size_t)N * 128 * 4;
    // aliases: dead after k_l1
    float* xh2 = xh1;
    float* es2 = es1;
    float* ed2 = ed1;

    hipMemsetAsync(deg, 0, (size_t)N * 4, stream);

    k_gemm1 <<<(N + 31) / 32,   256, 0, stream>>>(x, W1, as1, ad1, xh1, es1, ed1, N);
    k_hist  <<<2048,            256, 0, stream>>>(ei, E, N, deg);
    k_scan_a<<<NB,              256, 0, stream>>>(deg, rowp, bsum, N);
    k_scan_b<<<1,               512, 0, stream>>>(bsum, NB);
    k_scan_c<<<NB,              256, 0, stream>>>(rowp, bsum, fill, N);
    k_scatter<<<2048,           256, 0, stream>>>(ei, E, N, fill, csr);
    k_l1    <<<(N + 3) / 4,     256, 0, stream>>>(xh1, es1, ed1, rowp, deg, csr, b1, hbuf, N);
    k_gemm2 <<<(N + 255) / 256, 256, 0, stream>>>(hbuf, W2, as2, ad2, xh2, es2, ed2, N);
    k_l2    <<<(N + 3) / 4,     256, 0, stream>>>(xh2, es2, ed2, rowp, deg, csr, b2, out, N);
}

// Round 3
// 527.110 us; speedup vs baseline: 1.1775x; 1.1775x over previous
//
#include <hip/hip_runtime.h>

#define NEG_SLOPE 0.2f
#define EPSF 1e-16f

__device__ __forceinline__ float lrelu_exp(float a) {
    a = (a > 0.f) ? a : NEG_SLOPE * a;
    return __expf(a);
}

// ------- GEMM1: xh1 = x @ W1 (N x 128)(128 x 128), fused e_src1/e_dst1 --------
__global__ __launch_bounds__(256) void k_gemm1(const float* __restrict__ x,
                                               const float* __restrict__ W,
                                               const float* __restrict__ asrc,
                                               const float* __restrict__ adst,
                                               float* __restrict__ xh,
                                               float* __restrict__ es,
                                               float* __restrict__ ed, int N) {
    __shared__ float xs[32][132];   // 32 rows x 128, padded stride 132
    __shared__ float wsh[32][128];  // one 32-row k-panel of W
    const int t = threadIdx.x;
    const int row0 = blockIdx.x * 32;

    // stage x tile (32 x 128) as float4
    for (int i = t; i < 32 * 32; i += 256) {
        int r = i >> 5, c4 = i & 31;
        float4 v = make_float4(0.f, 0.f, 0.f, 0.f);
        if (row0 + r < N) v = ((const float4*)(x + (size_t)(row0 + r) * 128))[c4];
        *(float4*)&xs[r][c4 * 4] = v;
    }

    const int r0 = (t >> 5) * 4;   // 8 row-groups of 4
    const int c0 = (t & 31) * 4;   // 32 col-groups of 4
    float acc[4][4] = {};

    for (int kp = 0; kp < 128; kp += 32) {
        __syncthreads();           // x tile ready / previous panel consumed
        for (int i = t; i < 32 * 32; i += 256) {
            int kr = i >> 5, c4 = i & 31;
            ((float4*)&wsh[kr][0])[c4] =
                ((const float4*)(W + (size_t)(kp + kr) * 128))[c4];
        }
        __syncthreads();
        #pragma unroll
        for (int kk = 0; kk < 32; ++kk) {
            const float4 wv = *(const float4*)&wsh[kk][c0];
            const int k = kp + kk;
            #pragma unroll
            for (int i = 0; i < 4; ++i) {
                const float xv = xs[r0 + i][k];
                acc[i][0] += xv * wv.x;
                acc[i][1] += xv * wv.y;
                acc[i][2] += xv * wv.z;
                acc[i][3] += xv * wv.w;
            }
        }
    }

    // write xh tile
    #pragma unroll
    for (int i = 0; i < 4; ++i) {
        const int row = row0 + r0 + i;
        if (row < N) {
            *(float4*)(xh + (size_t)row * 128 + c0) =
                make_float4(acc[i][0], acc[i][1], acc[i][2], acc[i][3]);
        }
    }

    // fused e_src/e_dst: head = c0>>4, this thread's 4 cols live in one head
    const int head = c0 >> 4;
    const int cb   = c0 & 15;
    float4 av = *(const float4*)(asrc + head * 16 + cb);
    float4 bv = *(const float4*)(adst + head * 16 + cb);
    #pragma unroll
    for (int i = 0; i < 4; ++i) {
        float ps = acc[i][0] * av.x + acc[i][1] * av.y + acc[i][2] * av.z + acc[i][3] * av.w;
        float pd = acc[i][0] * bv.x + acc[i][1] * bv.y + acc[i][2] * bv.z + acc[i][3] * bv.w;
        ps += __shfl_xor(ps, 1, 64); ps += __shfl_xor(ps, 2, 64);
        pd += __shfl_xor(pd, 1, 64); pd += __shfl_xor(pd, 2, 64);
        const int row = row0 + r0 + i;
        if ((t & 3) == 0 && row < N) {
            es[row * 8 + head] = ps;
            ed[row * 8 + head] = pd;
        }
    }
}

// ------------------------- CSR build: histogram by dst -------------------------
__global__ void k_hist(const int* __restrict__ ei, int E, int N, int* __restrict__ deg) {
    const int Et = E + N;
    for (int e = blockIdx.x * blockDim.x + threadIdx.x; e < Et;
         e += gridDim.x * blockDim.x) {
        int d = (e < E) ? ei[E + e] : (e - E);   // self-loop tail
        atomicAdd(&deg[d], 1);
    }
}

__global__ __launch_bounds__(256) void k_scan_a(const int* __restrict__ deg,
                                                int* __restrict__ rowp,
                                                int* __restrict__ bsum, int N) {
    __shared__ int sd[256];
    const int t = threadIdx.x;
    const int i = blockIdx.x * 256 + t;
    const int v = (i < N) ? deg[i] : 0;
    sd[t] = v;
    __syncthreads();
    for (int off = 1; off < 256; off <<= 1) {
        int add = (t >= off) ? sd[t - off] : 0;
        __syncthreads();
        sd[t] += add;
        __syncthreads();
    }
    if (i < N) rowp[i] = sd[t] - v;              // exclusive within block
    if (t == 255) bsum[blockIdx.x] = sd[255];
}

__global__ __launch_bounds__(512) void k_scan_b(int* __restrict__ bsum, int NB) {
    __shared__ int sd[512];
    const int t = threadIdx.x;
    const int v = (t < NB) ? bsum[t] : 0;
    sd[t] = v;
    __syncthreads();
    for (int off = 1; off < 512; off <<= 1) {
        int add = (t >= off) ? sd[t - off] : 0;
        __syncthreads();
        sd[t] += add;
        __syncthreads();
    }
    if (t < NB) bsum[t] = sd[t] - v;             // exclusive block bases
}

__global__ __launch_bounds__(256) void k_scan_c(int* __restrict__ rowp,
                                                const int* __restrict__ bsum,
                                                int* __restrict__ fill, int N) {
    const int i = blockIdx.x * 256 + threadIdx.x;
    if (i >= N) return;
    const int v = rowp[i] + bsum[blockIdx.x];
    rowp[i] = v;
    fill[i] = v;
}

__global__ void k_scatter(const int* __restrict__ ei, int E, int N,
                          int* __restrict__ fill, int* __restrict__ csr) {
    const int Et = E + N;
    for (int e = blockIdx.x * blockDim.x + threadIdx.x; e < Et;
         e += gridDim.x * blockDim.x) {
        int s, d;
        if (e < E) { s = ei[e]; d = ei[E + e]; }
        else       { s = e - E; d = e - E; }
        const int pos = atomicAdd(&fill[d], 1);
        csr[pos] = s;
    }
}

// -------- layer-1 aggregate: one wave per dst node, 2 channels per lane --------
// Unroll-by-4: 4 independent edge gathers in flight (MLP), simple consume.
__global__ __launch_bounds__(256) void k_l1(const float* __restrict__ xh,
                                            const float* __restrict__ es,
                                            const float* __restrict__ ed,
                                            const int* __restrict__ rowp,
                                            const int* __restrict__ deg,
                                            const int* __restrict__ csr,
                                            const float* __restrict__ b1,
                                            float* __restrict__ hout, int N) {
    const int wave = threadIdx.x >> 6;
    const int lane = threadIdx.x & 63;
    const int n = blockIdx.x * 4 + wave;
    if (n >= N) return;
    const int h = lane >> 3;
    const float edv = ed[n * 8 + h];
    const int start = rowp[n];
    const int cnt = deg[n];

    float acc0 = 0.f, acc1 = 0.f, dsum = 0.f;
    const size_t co = (size_t)(lane * 2);
    int k = 0;
    for (; k + 4 <= cnt; k += 4) {
        const int s0 = csr[start + k];
        const int s1 = csr[start + k + 1];
        const int s2 = csr[start + k + 2];
        const int s3 = csr[start + k + 3];
        const float e0 = es[s0 * 8 + h];
        const float e1 = es[s1 * 8 + h];
        const float e2 = es[s2 * 8 + h];
        const float e3 = es[s3 * 8 + h];
        const float2 v0 = *(const float2*)(xh + (size_t)s0 * 128 + co);
        const float2 v1 = *(const float2*)(xh + (size_t)s1 * 128 + co);
        const float2 v2 = *(const float2*)(xh + (size_t)s2 * 128 + co);
        const float2 v3 = *(const float2*)(xh + (size_t)s3 * 128 + co);
        const float a0 = lrelu_exp(e0 + edv);
        const float a1 = lrelu_exp(e1 + edv);
        const float a2 = lrelu_exp(e2 + edv);
        const float a3 = lrelu_exp(e3 + edv);
        acc0 += a0 * v0.x + a1 * v1.x + a2 * v2.x + a3 * v3.x;
        acc1 += a0 * v0.y + a1 * v1.y + a2 * v2.y + a3 * v3.y;
        dsum += (a0 + a1) + (a2 + a3);
    }
    for (; k < cnt; ++k) {
        const int s = csr[start + k];
        const float ea = lrelu_exp(es[s * 8 + h] + edv);
        const float2 v = *(const float2*)(xh + (size_t)s * 128 + co);
        acc0 += ea * v.x;
        acc1 += ea * v.y;
        dsum += ea;
    }
    const float inv = 1.f / (dsum + EPSF);
    float o0 = acc0 * inv + b1[lane * 2];
    float o1 = acc1 * inv + b1[lane * 2 + 1];
    o0 = (o0 > 0.f) ? o0 : expm1f(o0);           // ELU
    o1 = (o1 > 0.f) ? o1 : expm1f(o1);
    *(float2*)(hout + (size_t)n * 128 + lane * 2) = make_float2(o0, o1);
}

// ------ GEMM2: xh2 = h @ W2 (N x 128)(128 x 40), fused e_src2/e_dst2 ---------
__global__ __launch_bounds__(256) void k_gemm2(const float* __restrict__ h,
                                               const float* __restrict__ W2,
                                               const float* __restrict__ as2,
                                               const float* __restrict__ ad2,
                                               float* __restrict__ xh2,
                                               float* __restrict__ es2,
                                               float* __restrict__ ed2, int N) {
    __shared__ float w[128 * 40];
    __shared__ float sa[40], sb[40];
    for (int i = threadIdx.x; i < 128 * 40 / 4; i += 256)
        ((float4*)w)[i] = ((const float4*)W2)[i];
    if (threadIdx.x < 40) { sa[threadIdx.x] = as2[threadIdx.x]; sb[threadIdx.x] = ad2[threadIdx.x]; }
    __syncthreads();
    const int n = blockIdx.x * 256 + threadIdx.x;
    if (n >= N) return;
    float acc[40];
    #pragma unroll
    for (int j = 0; j < 40; ++j) acc[j] = 0.f;
    const float4* hr = (const float4*)(h + (size_t)n * 128);
    for (int k4 = 0; k4 < 32; ++k4) {
        const float4 hv = hr[k4];
        const float hx[4] = {hv.x, hv.y, hv.z, hv.w};
        #pragma unroll
        for (int kk = 0; kk < 4; ++kk) {
            const float* wr = &w[(k4 * 4 + kk) * 40];
            #pragma unroll
            for (int j = 0; j < 40; j += 4) {
                const float4 wv = *(const float4*)&wr[j];
                acc[j]     += hx[kk] * wv.x;
                acc[j + 1] += hx[kk] * wv.y;
                acc[j + 2] += hx[kk] * wv.z;
                acc[j + 3] += hx[kk] * wv.w;
            }
        }
    }
    float4* op = (float4*)(xh2 + (size_t)n * 40);
    float s = 0.f, d = 0.f;
    #pragma unroll
    for (int j = 0; j < 10; ++j) {
        op[j] = make_float4(acc[4 * j], acc[4 * j + 1], acc[4 * j + 2], acc[4 * j + 3]);
        #pragma unroll
        for (int q = 0; q < 4; ++q) {
            s += acc[4 * j + q] * sa[4 * j + q];
            d += acc[4 * j + q] * sb[4 * j + q];
        }
    }
    es2[n] = s; ed2[n] = d;
}

// -------- layer-2 aggregate: one wave per dst node, lane = class channel --------
__global__ __launch_bounds__(256) void k_l2(const float* __restrict__ xh2,
                                            const float* __restrict__ es2,
                                            const float* __restrict__ ed2,
                                            const int* __restrict__ rowp,
                                            const int* __restrict__ deg,
                                            const int* __restrict__ csr,
                                            const float* __restrict__ b2,
                                            float* __restrict__ out, int N) {
    const int wave = threadIdx.x >> 6;
    const int lane = threadIdx.x & 63;
    const int n = blockIdx.x * 4 + wave;
    if (n >= N) return;
    const float edv = ed2[n];
    const int start = rowp[n];
    const int cnt = deg[n];
    const int l = (lane < 40) ? lane : 39;       // clamp; lanes >=40 discarded
    float acc = 0.f, dsum = 0.f;
    int k = 0;
    for (; k + 4 <= cnt; k += 4) {
        const int s0 = csr[start + k];
        const int s1 = csr[start + k + 1];
        const int s2 = csr[start + k + 2];
        const int s3 = csr[start + k + 3];
        const float e0 = es2[s0];
        const float e1 = es2[s1];
        const float e2 = es2[s2];
        const float e3 = es2[s3];
        const float v0 = xh2[(size_t)s0 * 40 + l];
        const float v1 = xh2[(size_t)s1 * 40 + l];
        const float v2 = xh2[(size_t)s2 * 40 + l];
        const float v3 = xh2[(size_t)s3 * 40 + l];
        const float a0 = lrelu_exp(e0 + edv);
        const float a1 = lrelu_exp(e1 + edv);
        const float a2 = lrelu_exp(e2 + edv);
        const float a3 = lrelu_exp(e3 + edv);
        acc += a0 * v0 + a1 * v1 + a2 * v2 + a3 * v3;
        dsum += (a0 + a1) + (a2 + a3);
    }
    for (; k < cnt; ++k) {
        const int s = csr[start + k];
        const float ea = lrelu_exp(es2[s] + edv);
        const float v = xh2[(size_t)s * 40 + l];
        acc += ea * v;
        dsum += ea;
    }
    if (lane < 40)
        out[(size_t)n * 40 + lane] = acc / (dsum + EPSF) + b2[lane];
}

extern "C" void kernel_launch(void* const* d_in, const int* in_sizes, int n_in,
                              void* d_out, int out_size, void* d_ws, size_t ws_size,
                              hipStream_t stream) {
    const float* x   = (const float*)d_in[0];
    const int*   ei  = (const int*)d_in[1];
    const float* W1  = (const float*)d_in[2];
    const float* as1 = (const float*)d_in[3];
    const float* ad1 = (const float*)d_in[4];
    const float* b1  = (const float*)d_in[5];
    const float* W2  = (const float*)d_in[6];
    const float* as2 = (const float*)d_in[7];
    const float* ad2 = (const float*)d_in[8];
    const float* b2  = (const float*)d_in[9];
    float* out = (float*)d_out;

    const int N  = in_sizes[0] / 128;
    const int E  = in_sizes[1] / 2;
    const int Et = E + N;
    const int NB = (N + 255) / 256;   // 391 for N=100000 (fits the 512-wide scan_b)

    // ---- workspace layout (~117 MB) ----
    char* p = (char*)d_ws;
    float* xh1  = (float*)p; p += (size_t)N * 128 * 4;
    float* es1  = (float*)p; p += (size_t)N * 8 * 4;
    float* ed1  = (float*)p; p += (size_t)N * 8 * 4;
    int*   deg  = (int*)p;   p += (size_t)N * 4;
    int*   rowp = (int*)p;   p += (size_t)N * 4;
    int*   fill = (int*)p;   p += (size_t)N * 4;
    int*   bsum = (int*)p;   p += 2048 * 4;
    int*   csr  = (int*)p;   p += (size_t)Et * 4;
    float* hbuf = (float*)p; p += (size_t)N * 128 * 4;
    // aliases: dead after k_l1
    float* xh2 = xh1;
    float* es2 = es1;
    float* ed2 = ed1;

    hipMemsetAsync(deg, 0, (size_t)N * 4, stream);

    k_gemm1 <<<(N + 31) / 32,   256, 0, stream>>>(x, W1, as1, ad1, xh1, es1, ed1, N);
    k_hist  <<<2048,            256, 0, stream>>>(ei, E, N, deg);
    k_scan_a<<<NB,              256, 0, stream>>>(deg, rowp, bsum, N);
    k_scan_b<<<1,               512, 0, stream>>>(bsum, NB);
    k_scan_c<<<NB,              256, 0, stream>>>(rowp, bsum, fill, N);
    k_scatter<<<2048,           256, 0, stream>>>(ei, E, N, fill, csr);
    k_l1    <<<(N + 3) / 4,     256, 0, stream>>>(xh1, es1, ed1, rowp, deg, csr, b1, hbuf, N);
    k_gemm2 <<<(N + 255) / 256, 256, 0, stream>>>(hbuf, W2, as2, ad2, xh2, es2, ed2, N);
    k_l2    <<<(N + 3) / 4,     256, 0, stream>>>(xh2, es2, ed2, rowp, deg, csr, b2, out, N);
}

// Round 4
// 470.045 us; speedup vs baseline: 1.3205x; 1.1214x over previous
//
#include <hip/hip_runtime.h>

#define NEG_SLOPE 0.2f
#define EPSF 1e-16f

__device__ __forceinline__ float lrelu_exp(float a) {
    a = (a > 0.f) ? a : NEG_SLOPE * a;
    return __expf(a);
}

__device__ __forceinline__ unsigned short f2bf(float f) {   // RNE
    unsigned u = __float_as_uint(f);
    u += 0x7fff + ((u >> 16) & 1);
    return (unsigned short)(u >> 16);
}

__device__ __forceinline__ float bf2f(unsigned short b) {
    return __uint_as_float(((unsigned)b) << 16);
}

// -- GEMM1: xh1 = x @ W1 (N x 128)(128 x 128) -> bf16, fused e_src1/e_dst1 ----
__global__ __launch_bounds__(256) void k_gemm1(const float* __restrict__ x,
                                               const float* __restrict__ W,
                                               const float* __restrict__ asrc,
                                               const float* __restrict__ adst,
                                               unsigned short* __restrict__ xhb,
                                               float* __restrict__ es,
                                               float* __restrict__ ed, int N) {
    __shared__ float xs[32][132];   // 32 rows x 128, padded stride 132
    __shared__ float wsh[32][128];  // one 32-row k-panel of W
    const int t = threadIdx.x;
    const int row0 = blockIdx.x * 32;

    // stage x tile (32 x 128) as float4
    for (int i = t; i < 32 * 32; i += 256) {
        int r = i >> 5, c4 = i & 31;
        float4 v = make_float4(0.f, 0.f, 0.f, 0.f);
        if (row0 + r < N) v = ((const float4*)(x + (size_t)(row0 + r) * 128))[c4];
        *(float4*)&xs[r][c4 * 4] = v;
    }

    const int r0 = (t >> 5) * 4;   // 8 row-groups of 4
    const int c0 = (t & 31) * 4;   // 32 col-groups of 4
    float acc[4][4] = {};

    for (int kp = 0; kp < 128; kp += 32) {
        __syncthreads();
        for (int i = t; i < 32 * 32; i += 256) {
            int kr = i >> 5, c4 = i & 31;
            ((float4*)&wsh[kr][0])[c4] =
                ((const float4*)(W + (size_t)(kp + kr) * 128))[c4];
        }
        __syncthreads();
        #pragma unroll
        for (int kk = 0; kk < 32; ++kk) {
            const float4 wv = *(const float4*)&wsh[kk][c0];
            const int k = kp + kk;
            #pragma unroll
            for (int i = 0; i < 4; ++i) {
                const float xv = xs[r0 + i][k];
                acc[i][0] += xv * wv.x;
                acc[i][1] += xv * wv.y;
                acc[i][2] += xv * wv.z;
                acc[i][3] += xv * wv.w;
            }
        }
    }

    // write xh tile (bf16 packed)
    #pragma unroll
    for (int i = 0; i < 4; ++i) {
        const int row = row0 + r0 + i;
        if (row < N) {
            ushort4 pk;
            pk.x = f2bf(acc[i][0]);
            pk.y = f2bf(acc[i][1]);
            pk.z = f2bf(acc[i][2]);
            pk.w = f2bf(acc[i][3]);
            *(ushort4*)(xhb + (size_t)row * 128 + c0) = pk;
        }
    }

    // fused e_src/e_dst from f32 accumulators
    const int head = c0 >> 4;
    const int cb   = c0 & 15;
    float4 av = *(const float4*)(asrc + head * 16 + cb);
    float4 bv = *(const float4*)(adst + head * 16 + cb);
    #pragma unroll
    for (int i = 0; i < 4; ++i) {
        float ps = acc[i][0] * av.x + acc[i][1] * av.y + acc[i][2] * av.z + acc[i][3] * av.w;
        float pd = acc[i][0] * bv.x + acc[i][1] * bv.y + acc[i][2] * bv.z + acc[i][3] * bv.w;
        ps += __shfl_xor(ps, 1, 64); ps += __shfl_xor(ps, 2, 64);
        pd += __shfl_xor(pd, 1, 64); pd += __shfl_xor(pd, 2, 64);
        const int row = row0 + r0 + i;
        if ((t & 3) == 0 && row < N) {
            es[row * 8 + head] = ps;
            ed[row * 8 + head] = pd;
        }
    }
}

// ------------------------- CSR build: histogram by dst -------------------------
__global__ void k_hist(const int* __restrict__ ei, int E, int N, int* __restrict__ deg) {
    const int Et = E + N;
    for (int e = blockIdx.x * blockDim.x + threadIdx.x; e < Et;
         e += gridDim.x * blockDim.x) {
        int d = (e < E) ? ei[E + e] : (e - E);   // self-loop tail
        atomicAdd(&deg[d], 1);
    }
}

__global__ __launch_bounds__(256) void k_scan_a(const int* __restrict__ deg,
                                                int* __restrict__ rowp,
                                                int* __restrict__ bsum, int N) {
    __shared__ int sd[256];
    const int t = threadIdx.x;
    const int i = blockIdx.x * 256 + t;
    const int v = (i < N) ? deg[i] : 0;
    sd[t] = v;
    __syncthreads();
    for (int off = 1; off < 256; off <<= 1) {
        int add = (t >= off) ? sd[t - off] : 0;
        __syncthreads();
        sd[t] += add;
        __syncthreads();
    }
    if (i < N) rowp[i] = sd[t] - v;              // exclusive within block
    if (t == 255) bsum[blockIdx.x] = sd[255];
}

__global__ __launch_bounds__(512) void k_scan_b(int* __restrict__ bsum, int NB) {
    __shared__ int sd[512];
    const int t = threadIdx.x;
    const int v = (t < NB) ? bsum[t] : 0;
    sd[t] = v;
    __syncthreads();
    for (int off = 1; off < 512; off <<= 1) {
        int add = (t >= off) ? sd[t - off] : 0;
        __syncthreads();
        sd[t] += add;
        __syncthreads();
    }
    if (t < NB) bsum[t] = sd[t] - v;             // exclusive block bases
}

__global__ __launch_bounds__(256) void k_scan_c(int* __restrict__ rowp,
                                                const int* __restrict__ bsum,
                                                int* __restrict__ fill, int N) {
    const int i = blockIdx.x * 256 + threadIdx.x;
    if (i >= N) return;
    const int v = rowp[i] + bsum[blockIdx.x];
    rowp[i] = v;
    fill[i] = v;
}

__global__ void k_scatter(const int* __restrict__ ei, int E, int N,
                          int* __restrict__ fill, int* __restrict__ csr) {
    const int Et = E + N;
    for (int e = blockIdx.x * blockDim.x + threadIdx.x; e < Et;
         e += gridDim.x * blockDim.x) {
        int s, d;
        if (e < E) { s = ei[e]; d = ei[E + e]; }
        else       { s = e - E; d = e - E; }
        const int pos = atomicAdd(&fill[d], 1);
        csr[pos] = s;
    }
}

// -------- layer-1 aggregate: one wave per dst node, 2 channels per lane --------
// bf16 gather (4B/lane), unroll-by-4 for MLP, f32 accumulation.
__global__ __launch_bounds__(256) void k_l1(const unsigned short* __restrict__ xhb,
                                            const float* __restrict__ es,
                                            const float* __restrict__ ed,
                                            const int* __restrict__ rowp,
                                            const int* __restrict__ deg,
                                            const int* __restrict__ csr,
                                            const float* __restrict__ b1,
                                            float* __restrict__ hout, int N) {
    const int wave = threadIdx.x >> 6;
    const int lane = threadIdx.x & 63;
    const int n = blockIdx.x * 4 + wave;
    if (n >= N) return;
    const int h = lane >> 3;
    const float edv = ed[n * 8 + h];
    const int start = rowp[n];
    const int cnt = deg[n];

    float acc0 = 0.f, acc1 = 0.f, dsum = 0.f;
    const size_t co = (size_t)(lane * 2);
    int k = 0;
    for (; k + 4 <= cnt; k += 4) {
        const int s0 = csr[start + k];
        const int s1 = csr[start + k + 1];
        const int s2 = csr[start + k + 2];
        const int s3 = csr[start + k + 3];
        const float e0 = es[s0 * 8 + h];
        const float e1 = es[s1 * 8 + h];
        const float e2 = es[s2 * 8 + h];
        const float e3 = es[s3 * 8 + h];
        const unsigned p0 = *(const unsigned*)(xhb + (size_t)s0 * 128 + co);
        const unsigned p1 = *(const unsigned*)(xhb + (size_t)s1 * 128 + co);
        const unsigned p2 = *(const unsigned*)(xhb + (size_t)s2 * 128 + co);
        const unsigned p3 = *(const unsigned*)(xhb + (size_t)s3 * 128 + co);
        const float a0 = lrelu_exp(e0 + edv);
        const float a1 = lrelu_exp(e1 + edv);
        const float a2 = lrelu_exp(e2 + edv);
        const float a3 = lrelu_exp(e3 + edv);
        acc0 += a0 * bf2f((unsigned short)(p0 & 0xffff))
              + a1 * bf2f((unsigned short)(p1 & 0xffff))
              + a2 * bf2f((unsigned short)(p2 & 0xffff))
              + a3 * bf2f((unsigned short)(p3 & 0xffff));
        acc1 += a0 * bf2f((unsigned short)(p0 >> 16))
              + a1 * bf2f((unsigned short)(p1 >> 16))
              + a2 * bf2f((unsigned short)(p2 >> 16))
              + a3 * bf2f((unsigned short)(p3 >> 16));
        dsum += (a0 + a1) + (a2 + a3);
    }
    for (; k < cnt; ++k) {
        const int s = csr[start + k];
        const float ea = lrelu_exp(es[s * 8 + h] + edv);
        const unsigned pv = *(const unsigned*)(xhb + (size_t)s * 128 + co);
        acc0 += ea * bf2f((unsigned short)(pv & 0xffff));
        acc1 += ea * bf2f((unsigned short)(pv >> 16));
        dsum += ea;
    }
    const float inv = 1.f / (dsum + EPSF);
    float o0 = acc0 * inv + b1[lane * 2];
    float o1 = acc1 * inv + b1[lane * 2 + 1];
    o0 = (o0 > 0.f) ? o0 : expm1f(o0);           // ELU
    o1 = (o1 > 0.f) ? o1 : expm1f(o1);
    *(float2*)(hout + (size_t)n * 128 + lane * 2) = make_float2(o0, o1);
}

// ------ GEMM2: xh2 = h @ W2 (N x 128)(128 x 40), fused e_src2/e_dst2 ---------
__global__ __launch_bounds__(256) void k_gemm2(const float* __restrict__ h,
                                               const float* __restrict__ W2,
                                               const float* __restrict__ as2,
                                               const float* __restrict__ ad2,
                                               float* __restrict__ xh2,
                                               float* __restrict__ es2,
                                               float* __restrict__ ed2, int N) {
    __shared__ float w[128 * 40];
    __shared__ float sa[40], sb[40];
    for (int i = threadIdx.x; i < 128 * 40 / 4; i += 256)
        ((float4*)w)[i] = ((const float4*)W2)[i];
    if (threadIdx.x < 40) { sa[threadIdx.x] = as2[threadIdx.x]; sb[threadIdx.x] = ad2[threadIdx.x]; }
    __syncthreads();
    const int n = blockIdx.x * 256 + threadIdx.x;
    if (n >= N) return;
    float acc[40];
    #pragma unroll
    for (int j = 0; j < 40; ++j) acc[j] = 0.f;
    const float4* hr = (const float4*)(h + (size_t)n * 128);
    for (int k4 = 0; k4 < 32; ++k4) {
        const float4 hv = hr[k4];
        const float hx[4] = {hv.x, hv.y, hv.z, hv.w};
        #pragma unroll
        for (int kk = 0; kk < 4; ++kk) {
            const float* wr = &w[(k4 * 4 + kk) * 40];
            #pragma unroll
            for (int j = 0; j < 40; j += 4) {
                const float4 wv = *(const float4*)&wr[j];
                acc[j]     += hx[kk] * wv.x;
                acc[j + 1] += hx[kk] * wv.y;
                acc[j + 2] += hx[kk] * wv.z;
                acc[j + 3] += hx[kk] * wv.w;
            }
        }
    }
    float4* op = (float4*)(xh2 + (size_t)n * 40);
    float s = 0.f, d = 0.f;
    #pragma unroll
    for (int j = 0; j < 10; ++j) {
        op[j] = make_float4(acc[4 * j], acc[4 * j + 1], acc[4 * j + 2], acc[4 * j + 3]);
        #pragma unroll
        for (int q = 0; q < 4; ++q) {
            s += acc[4 * j + q] * sa[4 * j + q];
            d += acc[4 * j + q] * sb[4 * j + q];
        }
    }
    es2[n] = s; ed2[n] = d;
}

// -------- layer-2 aggregate: one wave per dst node, lane = class channel --------
__global__ __launch_bounds__(256) void k_l2(const float* __restrict__ xh2,
                                            const float* __restrict__ es2,
                                            const float* __restrict__ ed2,
                                            const int* __restrict__ rowp,
                                            const int* __restrict__ deg,
                                            const int* __restrict__ csr,
                                            const float* __restrict__ b2,
                                            float* __restrict__ out, int N) {
    const int wave = threadIdx.x >> 6;
    const int lane = threadIdx.x & 63;
    const int n = blockIdx.x * 4 + wave;
    if (n >= N) return;
    const float edv = ed2[n];
    const int start = rowp[n];
    const int cnt = deg[n];
    const int l = (lane < 40) ? lane : 39;       // clamp; lanes >=40 discarded
    float acc = 0.f, dsum = 0.f;
    int k = 0;
    for (; k + 4 <= cnt; k += 4) {
        const int s0 = csr[start + k];
        const int s1 = csr[start + k + 1];
        const int s2 = csr[start + k + 2];
        const int s3 = csr[start + k + 3];
        const float e0 = es2[s0];
        const float e1 = es2[s1];
        const float e2 = es2[s2];
        const float e3 = es2[s3];
        const float v0 = xh2[(size_t)s0 * 40 + l];
        const float v1 = xh2[(size_t)s1 * 40 + l];
        const float v2 = xh2[(size_t)s2 * 40 + l];
        const float v3 = xh2[(size_t)s3 * 40 + l];
        const float a0 = lrelu_exp(e0 + edv);
        const float a1 = lrelu_exp(e1 + edv);
        const float a2 = lrelu_exp(e2 + edv);
        const float a3 = lrelu_exp(e3 + edv);
        acc += a0 * v0 + a1 * v1 + a2 * v2 + a3 * v3;
        dsum += (a0 + a1) + (a2 + a3);
    }
    for (; k < cnt; ++k) {
        const int s = csr[start + k];
        const float ea = lrelu_exp(es2[s] + edv);
        const float v = xh2[(size_t)s * 40 + l];
        acc += ea * v;
        dsum += ea;
    }
    if (lane < 40)
        out[(size_t)n * 40 + lane] = acc / (dsum + EPSF) + b2[lane];
}

extern "C" void kernel_launch(void* const* d_in, const int* in_sizes, int n_in,
                              void* d_out, int out_size, void* d_ws, size_t ws_size,
                              hipStream_t stream) {
    const float* x   = (const float*)d_in[0];
    const int*   ei  = (const int*)d_in[1];
    const float* W1  = (const float*)d_in[2];
    const float* as1 = (const float*)d_in[3];
    const float* ad1 = (const float*)d_in[4];
    const float* b1  = (const float*)d_in[5];
    const float* W2  = (const float*)d_in[6];
    const float* as2 = (const float*)d_in[7];
    const float* ad2 = (const float*)d_in[8];
    const float* b2  = (const float*)d_in[9];
    float* out = (float*)d_out;

    const int N  = in_sizes[0] / 128;
    const int E  = in_sizes[1] / 2;
    const int Et = E + N;
    const int NB = (N + 255) / 256;

    // ---- workspace layout ----
    char* p = (char*)d_ws;
    unsigned short* xhb = (unsigned short*)p; p += (size_t)N * 128 * 2;   // bf16 xh1
    float* es1  = (float*)p; p += (size_t)N * 8 * 4;
    float* ed1  = (float*)p; p += (size_t)N * 8 * 4;
    int*   deg  = (int*)p;   p += (size_t)N * 4;
    int*   rowp = (int*)p;   p += (size_t)N * 4;
    int*   fill = (int*)p;   p += (size_t)N * 4;
    int*   bsum = (int*)p;   p += 2048 * 4;
    int*   csr  = (int*)p;   p += (size_t)Et * 4;
    float* hbuf = (float*)p; p += (size_t)N * 128 * 4;
    float* xh2  = (float*)p; p += (size_t)N * 40 * 4;
    // aliases: dead after k_l1
    float* es2 = es1;
    float* ed2 = ed1;

    hipMemsetAsync(deg, 0, (size_t)N * 4, stream);

    k_gemm1 <<<(N + 31) / 32,   256, 0, stream>>>(x, W1, as1, ad1, xhb, es1, ed1, N);
    k_hist  <<<2048,            256, 0, stream>>>(ei, E, N, deg);
    k_scan_a<<<NB,              256, 0, stream>>>(deg, rowp, bsum, N);
    k_scan_b<<<1,               512, 0, stream>>>(bsum, NB);
    k_scan_c<<<NB,              256, 0, stream>>>(rowp, bsum, fill, N);
    k_scatter<<<2048,           256, 0, stream>>>(ei, E, N, fill, csr);
    k_l1    <<<(N + 3) / 4,     256, 0, stream>>>(xhb, es1, ed1, rowp, deg, csr, b1, hbuf, N);
    k_gemm2 <<<(N + 255) / 256, 256, 0, stream>>>(hbuf, W2, as2, ad2, xh2, es2, ed2, N);
    k_l2    <<<(N + 3) / 4,     256, 0, stream>>>(xh2, es2, ed2, rowp, deg, csr, b2, out, N);
}

// Round 5
// 307.158 us; speedup vs baseline: 2.0207x; 1.5303x over previous
//
#include <hip/hip_runtime.h>

#define NEG_SLOPE 0.2f
#define EPSF 1e-16f
#define ABLK 512
#define SHIFT 8

__device__ __forceinline__ float lrelu_exp(float a) {
    a = (a > 0.f) ? a : NEG_SLOPE * a;
    return __expf(a);
}

__device__ __forceinline__ unsigned short f2bf(float f) {   // RNE
    unsigned u = __float_as_uint(f);
    u += 0x7fff + ((u >> 16) & 1);
    return (unsigned short)(u >> 16);
}

__device__ __forceinline__ float bf2f(unsigned short b) {
    return __uint_as_float(((unsigned)b) << 16);
}

// -- GEMM1: xh1 = x @ W1 (N x 128)(128 x 128) -> bf16, fused e_src1/e_dst1 ----
__global__ __launch_bounds__(256) void k_gemm1(const float* __restrict__ x,
                                               const float* __restrict__ W,
                                               const float* __restrict__ asrc,
                                               const float* __restrict__ adst,
                                               unsigned short* __restrict__ xhb,
                                               float* __restrict__ es,
                                               float* __restrict__ ed, int N) {
    __shared__ float xs[32][132];
    __shared__ float wsh[32][128];
    const int t = threadIdx.x;
    const int row0 = blockIdx.x * 32;

    for (int i = t; i < 32 * 32; i += 256) {
        int r = i >> 5, c4 = i & 31;
        float4 v = make_float4(0.f, 0.f, 0.f, 0.f);
        if (row0 + r < N) v = ((const float4*)(x + (size_t)(row0 + r) * 128))[c4];
        *(float4*)&xs[r][c4 * 4] = v;
    }

    const int r0 = (t >> 5) * 4;
    const int c0 = (t & 31) * 4;
    float acc[4][4] = {};

    for (int kp = 0; kp < 128; kp += 32) {
        __syncthreads();
        for (int i = t; i < 32 * 32; i += 256) {
            int kr = i >> 5, c4 = i & 31;
            ((float4*)&wsh[kr][0])[c4] =
                ((const float4*)(W + (size_t)(kp + kr) * 128))[c4];
        }
        __syncthreads();
        #pragma unroll
        for (int kk = 0; kk < 32; ++kk) {
            const float4 wv = *(const float4*)&wsh[kk][c0];
            const int k = kp + kk;
            #pragma unroll
            for (int i = 0; i < 4; ++i) {
                const float xv = xs[r0 + i][k];
                acc[i][0] += xv * wv.x;
                acc[i][1] += xv * wv.y;
                acc[i][2] += xv * wv.z;
                acc[i][3] += xv * wv.w;
            }
        }
    }

    #pragma unroll
    for (int i = 0; i < 4; ++i) {
        const int row = row0 + r0 + i;
        if (row < N) {
            ushort4 pk;
            pk.x = f2bf(acc[i][0]);
            pk.y = f2bf(acc[i][1]);
            pk.z = f2bf(acc[i][2]);
            pk.w = f2bf(acc[i][3]);
            *(ushort4*)(xhb + (size_t)row * 128 + c0) = pk;
        }
    }

    const int head = c0 >> 4;
    const int cb   = c0 & 15;
    float4 av = *(const float4*)(asrc + head * 16 + cb);
    float4 bv = *(const float4*)(adst + head * 16 + cb);
    #pragma unroll
    for (int i = 0; i < 4; ++i) {
        float ps = acc[i][0] * av.x + acc[i][1] * av.y + acc[i][2] * av.z + acc[i][3] * av.w;
        float pd = acc[i][0] * bv.x + acc[i][1] * bv.y + acc[i][2] * bv.z + acc[i][3] * bv.w;
        ps += __shfl_xor(ps, 1, 64); ps += __shfl_xor(ps, 2, 64);
        pd += __shfl_xor(pd, 1, 64); pd += __shfl_xor(pd, 2, 64);
        const int row = row0 + r0 + i;
        if ((t & 3) == 0 && row < N) {
            es[row * 8 + head] = ps;
            ed[row * 8 + head] = pd;
        }
    }
}

// ---------- CSR build, stage A: per-block coarse-bucket histogram (LDS) --------
__global__ __launch_bounds__(256) void k_bhist(const int* __restrict__ ei, int E, int N,
                                               int NBK, int* __restrict__ H) {
    __shared__ int hist[512];
    const int t = threadIdx.x;
    for (int i = t; i < NBK; i += 256) hist[i] = 0;
    __syncthreads();
    const int Et = E + N;
    for (int e = blockIdx.x * 256 + t; e < Et; e += ABLK * 256) {
        int d = (e < E) ? ei[E + e] : (e - E);   // self-loop tail
        atomicAdd(&hist[d >> SHIFT], 1);
    }
    __syncthreads();
    for (int i = t; i < NBK; i += 256)
        H[(size_t)i * ABLK + blockIdx.x] = hist[i];
}

// stage A-scan 1: exclusive scan of each bucket's per-block counts; total -> BT
__global__ __launch_bounds__(512) void k_scanH(int* __restrict__ H, int* __restrict__ BT) {
    __shared__ int sd[512];
    const int t = threadIdx.x;
    int* row = H + (size_t)blockIdx.x * ABLK;
    const int v = row[t];
    sd[t] = v;
    __syncthreads();
    for (int off = 1; off < 512; off <<= 1) {
        int add = (t >= off) ? sd[t - off] : 0;
        __syncthreads();
        sd[t] += add;
        __syncthreads();
    }
    row[t] = sd[t] - v;
    if (t == 511) BT[blockIdx.x] = sd[511];
}

// stage A-scan 2: exclusive scan of bucket totals -> BB; BB[NBK] = Et
__global__ __launch_bounds__(512) void k_scanBT(const int* __restrict__ BT,
                                                int* __restrict__ BB, int NBK) {
    __shared__ int sd[512];
    const int t = threadIdx.x;
    const int v = (t < NBK) ? BT[t] : 0;
    sd[t] = v;
    __syncthreads();
    for (int off = 1; off < 512; off <<= 1) {
        int add = (t >= off) ? sd[t - off] : 0;
        __syncthreads();
        sd[t] += add;
        __syncthreads();
    }
    if (t < NBK) BB[t] = sd[t] - v;
    if (t == 511) BB[NBK] = sd[511];
}

// stage A2: scatter (src,dst) into bucket-grouped E2 (LDS ranks, no global atomics)
__global__ __launch_bounds__(256) void k_bscat(const int* __restrict__ ei, int E, int N,
                                               int NBK, const int* __restrict__ H,
                                               const int* __restrict__ BB,
                                               uint2* __restrict__ E2) {
    __shared__ int cnt[512];
    __shared__ int base[512];
    const int t = threadIdx.x;
    for (int i = t; i < NBK; i += 256) {
        cnt[i] = 0;
        base[i] = BB[i] + H[(size_t)i * ABLK + blockIdx.x];
    }
    __syncthreads();
    const int Et = E + N;
    for (int e = blockIdx.x * 256 + t; e < Et; e += ABLK * 256) {
        int s, d;
        if (e < E) { s = ei[e]; d = ei[E + e]; }
        else       { s = e - E; d = e - E; }
        const int b = d >> SHIFT;
        const int r = atomicAdd(&cnt[b], 1);
        E2[base[b] + r] = make_uint2((unsigned)s, (unsigned)d);
    }
}

// stage B: per-bucket fine CSR (deg, rowp, csr) — LDS count+scan, no global atomics
__global__ __launch_bounds__(256) void k_bcsr(const uint2* __restrict__ E2,
                                              const int* __restrict__ BB, int N,
                                              int* __restrict__ deg,
                                              int* __restrict__ rowp,
                                              int* __restrict__ csr) {
    __shared__ int cnt[256];
    __shared__ int sc[256];
    __shared__ int rp[256];
    __shared__ int fl[256];
    const int t = threadIdx.x;
    const int b = blockIdx.x;
    const int lo = BB[b], hi = BB[b + 1];
    const int base_d = b << SHIFT;
    cnt[t] = 0; fl[t] = 0;
    __syncthreads();
    for (int i = lo + t; i < hi; i += 256)
        atomicAdd(&cnt[E2[i].y & 255], 1);
    __syncthreads();
    const int v = cnt[t];
    sc[t] = v;
    __syncthreads();
    for (int off = 1; off < 256; off <<= 1) {
        int add = (t >= off) ? sc[t - off] : 0;
        __syncthreads();
        sc[t] += add;
        __syncthreads();
    }
    rp[t] = sc[t] - v;                    // exclusive within bucket
    const int d = base_d + t;
    if (d < N) { deg[d] = v; rowp[d] = lo + rp[t]; }
    __syncthreads();
    for (int i = lo + t; i < hi; i += 256) {
        const uint2 e = E2[i];
        const int ld = e.y & 255;
        const int r = atomicAdd(&fl[ld], 1);
        csr[lo + rp[ld] + r] = (int)e.x;
    }
}

// -------- layer-1 aggregate: one wave per dst node, 2 channels per lane --------
__global__ __launch_bounds__(256) void k_l1(const unsigned short* __restrict__ xhb,
                                            const float* __restrict__ es,
                                            const float* __restrict__ ed,
                                            const int* __restrict__ rowp,
                                            const int* __restrict__ deg,
                                            const int* __restrict__ csr,
                                            const float* __restrict__ b1,
                                            float* __restrict__ hout, int N) {
    const int wave = threadIdx.x >> 6;
    const int lane = threadIdx.x & 63;
    const int n = blockIdx.x * 4 + wave;
    if (n >= N) return;
    const int h = lane >> 3;
    const float edv = ed[n * 8 + h];
    const int start = rowp[n];
    const int cnt = deg[n];

    float acc0 = 0.f, acc1 = 0.f, dsum = 0.f;
    const size_t co = (size_t)(lane * 2);
    int k = 0;
    for (; k + 4 <= cnt; k += 4) {
        const int s0 = csr[start + k];
        const int s1 = csr[start + k + 1];
        const int s2 = csr[start + k + 2];
        const int s3 = csr[start + k + 3];
        const float e0 = es[s0 * 8 + h];
        const float e1 = es[s1 * 8 + h];
        const float e2 = es[s2 * 8 + h];
        const float e3 = es[s3 * 8 + h];
        const unsigned p0 = *(const unsigned*)(xhb + (size_t)s0 * 128 + co);
        const unsigned p1 = *(const unsigned*)(xhb + (size_t)s1 * 128 + co);
        const unsigned p2 = *(const unsigned*)(xhb + (size_t)s2 * 128 + co);
        const unsigned p3 = *(const unsigned*)(xhb + (size_t)s3 * 128 + co);
        const float a0 = lrelu_exp(e0 + edv);
        const float a1 = lrelu_exp(e1 + edv);
        const float a2 = lrelu_exp(e2 + edv);
        const float a3 = lrelu_exp(e3 + edv);
        acc0 += a0 * bf2f((unsigned short)(p0 & 0xffff))
              + a1 * bf2f((unsigned short)(p1 & 0xffff))
              + a2 * bf2f((unsigned short)(p2 & 0xffff))
              + a3 * bf2f((unsigned short)(p3 & 0xffff));
        acc1 += a0 * bf2f((unsigned short)(p0 >> 16))
              + a1 * bf2f((unsigned short)(p1 >> 16))
              + a2 * bf2f((unsigned short)(p2 >> 16))
              + a3 * bf2f((unsigned short)(p3 >> 16));
        dsum += (a0 + a1) + (a2 + a3);
    }
    for (; k < cnt; ++k) {
        const int s = csr[start + k];
        const float ea = lrelu_exp(es[s * 8 + h] + edv);
        const unsigned pv = *(const unsigned*)(xhb + (size_t)s * 128 + co);
        acc0 += ea * bf2f((unsigned short)(pv & 0xffff));
        acc1 += ea * bf2f((unsigned short)(pv >> 16));
        dsum += ea;
    }
    const float inv = 1.f / (dsum + EPSF);
    float o0 = acc0 * inv + b1[lane * 2];
    float o1 = acc1 * inv + b1[lane * 2 + 1];
    o0 = (o0 > 0.f) ? o0 : expm1f(o0);
    o1 = (o1 > 0.f) ? o1 : expm1f(o1);
    *(float2*)(hout + (size_t)n * 128 + lane * 2) = make_float2(o0, o1);
}

// ------ GEMM2: xh2 = h @ W2 (N x 128)(128 x 40), fused e_src2/e_dst2 ---------
__global__ __launch_bounds__(256) void k_gemm2(const float* __restrict__ h,
                                               const float* __restrict__ W2,
                                               const float* __restrict__ as2,
                                               const float* __restrict__ ad2,
                                               float* __restrict__ xh2,
                                               float* __restrict__ es2,
                                               float* __restrict__ ed2, int N) {
    __shared__ float w[128 * 40];
    __shared__ float sa[40], sb[40];
    for (int i = threadIdx.x; i < 128 * 40 / 4; i += 256)
        ((float4*)w)[i] = ((const float4*)W2)[i];
    if (threadIdx.x < 40) { sa[threadIdx.x] = as2[threadIdx.x]; sb[threadIdx.x] = ad2[threadIdx.x]; }
    __syncthreads();
    const int n = blockIdx.x * 256 + threadIdx.x;
    if (n >= N) return;
    float acc[40];
    #pragma unroll
    for (int j = 0; j < 40; ++j) acc[j] = 0.f;
    const float4* hr = (const float4*)(h + (size_t)n * 128);
    for (int k4 = 0; k4 < 32; ++k4) {
        const float4 hv = hr[k4];
        const float hx[4] = {hv.x, hv.y, hv.z, hv.w};
        #pragma unroll
        for (int kk = 0; kk < 4; ++kk) {
            const float* wr = &w[(k4 * 4 + kk) * 40];
            #pragma unroll
            for (int j = 0; j < 40; j += 4) {
                const float4 wv = *(const float4*)&wr[j];
                acc[j]     += hx[kk] * wv.x;
                acc[j + 1] += hx[kk] * wv.y;
                acc[j + 2] += hx[kk] * wv.z;
                acc[j + 3] += hx[kk] * wv.w;
            }
        }
    }
    float4* op = (float4*)(xh2 + (size_t)n * 40);
    float s = 0.f, d = 0.f;
    #pragma unroll
    for (int j = 0; j < 10; ++j) {
        op[j] = make_float4(acc[4 * j], acc[4 * j + 1], acc[4 * j + 2], acc[4 * j + 3]);
        #pragma unroll
        for (int q = 0; q < 4; ++q) {
            s += acc[4 * j + q] * sa[4 * j + q];
            d += acc[4 * j + q] * sb[4 * j + q];
        }
    }
    es2[n] = s; ed2[n] = d;
}

// -------- layer-2 aggregate: one wave per dst node, lane = class channel --------
__global__ __launch_bounds__(256) void k_l2(const float* __restrict__ xh2,
                                            const float* __restrict__ es2,
                                            const float* __restrict__ ed2,
                                            const int* __restrict__ rowp,
                                            const int* __restrict__ deg,
                                            const int* __restrict__ csr,
                                            const float* __restrict__ b2,
                                            float* __restrict__ out, int N) {
    const int wave = threadIdx.x >> 6;
    const int lane = threadIdx.x & 63;
    const int n = blockIdx.x * 4 + wave;
    if (n >= N) return;
    const float edv = ed2[n];
    const int start = rowp[n];
    const int cnt = deg[n];
    const int l = (lane < 40) ? lane : 39;
    float acc = 0.f, dsum = 0.f;
    int k = 0;
    for (; k + 4 <= cnt; k += 4) {
        const int s0 = csr[start + k];
        const int s1 = csr[start + k + 1];
        const int s2 = csr[start + k + 2];
        const int s3 = csr[start + k + 3];
        const float e0 = es2[s0];
        const float e1 = es2[s1];
        const float e2 = es2[s2];
        const float e3 = es2[s3];
        const float v0 = xh2[(size_t)s0 * 40 + l];
        const float v1 = xh2[(size_t)s1 * 40 + l];
        const float v2 = xh2[(size_t)s2 * 40 + l];
        const float v3 = xh2[(size_t)s3 * 40 + l];
        const float a0 = lrelu_exp(e0 + edv);
        const float a1 = lrelu_exp(e1 + edv);
        const float a2 = lrelu_exp(e2 + edv);
        const float a3 = lrelu_exp(e3 + edv);
        acc += a0 * v0 + a1 * v1 + a2 * v2 + a3 * v3;
        dsum += (a0 + a1) + (a2 + a3);
    }
    for (; k < cnt; ++k) {
        const int s = csr[start + k];
        const float ea = lrelu_exp(es2[s] + edv);
        const float v = xh2[(size_t)s * 40 + l];
        acc += ea * v;
        dsum += ea;
    }
    if (lane < 40)
        out[(size_t)n * 40 + lane] = acc / (dsum + EPSF) + b2[lane];
}

extern "C" void kernel_launch(void* const* d_in, const int* in_sizes, int n_in,
                              void* d_out, int out_size, void* d_ws, size_t ws_size,
                              hipStream_t stream) {
    const float* x   = (const float*)d_in[0];
    const int*   ei  = (const int*)d_in[1];
    const float* W1  = (const float*)d_in[2];
    const float* as1 = (const float*)d_in[3];
    const float* ad1 = (const float*)d_in[4];
    const float* b1  = (const float*)d_in[5];
    const float* W2  = (const float*)d_in[6];
    const float* as2 = (const float*)d_in[7];
    const float* ad2 = (const float*)d_in[8];
    const float* b2  = (const float*)d_in[9];
    float* out = (float*)d_out;

    const int N   = in_sizes[0] / 128;
    const int E   = in_sizes[1] / 2;
    const int Et  = E + N;
    const int NBK = (N + 255) >> SHIFT;   // 391 coarse buckets (<= 512)

    // ---- workspace layout (~108 MB) ----
    char* p = (char*)d_ws;
    unsigned short* xhb = (unsigned short*)p; p += (size_t)N * 128 * 2;
    float* es1  = (float*)p; p += (size_t)N * 8 * 4;
    float* ed1  = (float*)p; p += (size_t)N * 8 * 4;
    int*   deg  = (int*)p;   p += (size_t)N * 4;
    int*   rowp = (int*)p;   p += (size_t)N * 4;
    int*   csr  = (int*)p;   p += (size_t)Et * 4;
    int*   H    = (int*)p;   p += (size_t)512 * ABLK * 4;
    int*   BT   = (int*)p;   p += 512 * 4;
    int*   BB   = (int*)p;   p += 512 * 4;
    float* hbuf = (float*)p; p += (size_t)N * 128 * 4;
    float* xh2  = (float*)p; p += (size_t)N * 40 * 4;
    // E2 aliases hbuf: dead after k_bcsr, hbuf first written by k_l1 (stream-ordered)
    uint2* E2 = (uint2*)hbuf;
    float* es2 = es1;
    float* ed2 = ed1;

    k_gemm1 <<<(N + 31) / 32,   256, 0, stream>>>(x, W1, as1, ad1, xhb, es1, ed1, N);
    k_bhist <<<ABLK,            256, 0, stream>>>(ei, E, N, NBK, H);
    k_scanH <<<NBK,             512, 0, stream>>>(H, BT);
    k_scanBT<<<1,               512, 0, stream>>>(BT, BB, NBK);
    k_bscat <<<ABLK,            256, 0, stream>>>(ei, E, N, NBK, H, BB, E2);
    k_bcsr  <<<NBK,             256, 0, stream>>>(E2, BB, N, deg, rowp, csr);
    k_l1    <<<(N + 3) / 4,     256, 0, stream>>>(xhb, es1, ed1, rowp, deg, csr, b1, hbuf, N);
    k_gemm2 <<<(N + 255) / 256, 256, 0, stream>>>(hbuf, W2, as2, ad2, xh2, es2, ed2, N);
    k_l2    <<<(N + 3) / 4,     256, 0, stream>>>(xh2, es2, ed2, rowp, deg, csr, b2, out, N);
}

// Round 7
// 280.739 us; speedup vs baseline: 2.2109x; 1.0941x over previous
//
#include <hip/hip_runtime.h>

#define NEG_SLOPE 0.2f
#define EPSF 1e-16f
#define ABLK 512
#define SHIFT 8
// ds_swizzle BitMode pattern: src_lane = (lane & 0x18) | e  (within 32-half;
// groups of 8 never cross the half boundary, bit5 is preserved)
#define SWZ(e) (((e) << 5) | 0x18)

__device__ __forceinline__ float lrelu_exp(float a) {
    a = (a > 0.f) ? a : NEG_SLOPE * a;
    return __expf(a);
}

__device__ __forceinline__ unsigned short f2bf(float f) {   // RNE
    unsigned u = __float_as_uint(f);
    u += 0x7fff + ((u >> 16) & 1);
    return (unsigned short)(u >> 16);
}

template <int PAT>
__device__ __forceinline__ float swz_f(float v) {
    return __uint_as_float((unsigned)__builtin_amdgcn_ds_swizzle(__float_as_int(v), PAT));
}
template <int PAT>
__device__ __forceinline__ int swz_i(int v) {
    return __builtin_amdgcn_ds_swizzle(v, PAT);
}

// -- GEMM1: xh1 = x @ W1 (N x 128)(128 x 128) -> bf16, fused e_src1/e_dst1 ----
__global__ __launch_bounds__(256) void k_gemm1(const float* __restrict__ x,
                                               const float* __restrict__ W,
                                               const float* __restrict__ asrc,
                                               const float* __restrict__ adst,
                                               unsigned short* __restrict__ xhb,
                                               float* __restrict__ es,
                                               float* __restrict__ ed, int N) {
    __shared__ float xs[32][132];
    __shared__ float wsh[32][128];
    const int t = threadIdx.x;
    const int row0 = blockIdx.x * 32;

    for (int i = t; i < 32 * 32; i += 256) {
        int r = i >> 5, c4 = i & 31;
        float4 v = make_float4(0.f, 0.f, 0.f, 0.f);
        if (row0 + r < N) v = ((const float4*)(x + (size_t)(row0 + r) * 128))[c4];
        *(float4*)&xs[r][c4 * 4] = v;
    }

    const int r0 = (t >> 5) * 4;
    const int c0 = (t & 31) * 4;
    float acc[4][4] = {};

    for (int kp = 0; kp < 128; kp += 32) {
        __syncthreads();
        for (int i = t; i < 32 * 32; i += 256) {
            int kr = i >> 5, c4 = i & 31;
            ((float4*)&wsh[kr][0])[c4] =
                ((const float4*)(W + (size_t)(kp + kr) * 128))[c4];
        }
        __syncthreads();
        #pragma unroll
        for (int kk = 0; kk < 32; ++kk) {
            const float4 wv = *(const float4*)&wsh[kk][c0];
            const int k = kp + kk;
            #pragma unroll
            for (int i = 0; i < 4; ++i) {
                const float xv = xs[r0 + i][k];
                acc[i][0] += xv * wv.x;
                acc[i][1] += xv * wv.y;
                acc[i][2] += xv * wv.z;
                acc[i][3] += xv * wv.w;
            }
        }
    }

    #pragma unroll
    for (int i = 0; i < 4; ++i) {
        const int row = row0 + r0 + i;
        if (row < N) {
            ushort4 pk;
            pk.x = f2bf(acc[i][0]);
            pk.y = f2bf(acc[i][1]);
            pk.z = f2bf(acc[i][2]);
            pk.w = f2bf(acc[i][3]);
            *(ushort4*)(xhb + (size_t)row * 128 + c0) = pk;
        }
    }

    const int head = c0 >> 4;
    const int cb   = c0 & 15;
    float4 av = *(const float4*)(asrc + head * 16 + cb);
    float4 bv = *(const float4*)(adst + head * 16 + cb);
    #pragma unroll
    for (int i = 0; i < 4; ++i) {
        float ps = acc[i][0] * av.x + acc[i][1] * av.y + acc[i][2] * av.z + acc[i][3] * av.w;
        float pd = acc[i][0] * bv.x + acc[i][1] * bv.y + acc[i][2] * bv.z + acc[i][3] * bv.w;
        ps += __shfl_xor(ps, 1, 64); ps += __shfl_xor(ps, 2, 64);
        pd += __shfl_xor(pd, 1, 64); pd += __shfl_xor(pd, 2, 64);
        const int row = row0 + r0 + i;
        if ((t & 3) == 0 && row < N) {
            es[row * 8 + head] = ps;
            ed[row * 8 + head] = pd;
        }
    }
}

// ---------- CSR build, stage A: per-block coarse-bucket histogram (LDS) --------
__global__ __launch_bounds__(256) void k_bhist(const int* __restrict__ ei, int E, int N,
                                               int NBK, int* __restrict__ H) {
    __shared__ int hist[512];
    const int t = threadIdx.x;
    for (int i = t; i < NBK; i += 256) hist[i] = 0;
    __syncthreads();
    const int Et = E + N;
    for (int e = blockIdx.x * 256 + t; e < Et; e += ABLK * 256) {
        int d = (e < E) ? ei[E + e] : (e - E);
        atomicAdd(&hist[d >> SHIFT], 1);
    }
    __syncthreads();
    for (int i = t; i < NBK; i += 256)
        H[(size_t)i * ABLK + blockIdx.x] = hist[i];
}

__global__ __launch_bounds__(512) void k_scanH(int* __restrict__ H, int* __restrict__ BT) {
    __shared__ int sd[512];
    const int t = threadIdx.x;
    int* row = H + (size_t)blockIdx.x * ABLK;
    const int v = row[t];
    sd[t] = v;
    __syncthreads();
    for (int off = 1; off < 512; off <<= 1) {
        int add = (t >= off) ? sd[t - off] : 0;
        __syncthreads();
        sd[t] += add;
        __syncthreads();
    }
    row[t] = sd[t] - v;
    if (t == 511) BT[blockIdx.x] = sd[511];
}

__global__ __launch_bounds__(512) void k_scanBT(const int* __restrict__ BT,
                                                int* __restrict__ BB, int NBK) {
    __shared__ int sd[512];
    const int t = threadIdx.x;
    const int v = (t < NBK) ? BT[t] : 0;
    sd[t] = v;
    __syncthreads();
    for (int off = 1; off < 512; off <<= 1) {
        int add = (t >= off) ? sd[t - off] : 0;
        __syncthreads();
        sd[t] += add;
        __syncthreads();
    }
    if (t < NBK) BB[t] = sd[t] - v;
    if (t == 511) BB[NBK] = sd[511];
}

__global__ __launch_bounds__(256) void k_bscat(const int* __restrict__ ei, int E, int N,
                                               int NBK, const int* __restrict__ H,
                                               const int* __restrict__ BB,
                                               uint2* __restrict__ E2) {
    __shared__ int cnt[512];
    __shared__ int base[512];
    const int t = threadIdx.x;
    for (int i = t; i < NBK; i += 256) {
        cnt[i] = 0;
        base[i] = BB[i] + H[(size_t)i * ABLK + blockIdx.x];
    }
    __syncthreads();
    const int Et = E + N;
    for (int e = blockIdx.x * 256 + t; e < Et; e += ABLK * 256) {
        int s, d;
        if (e < E) { s = ei[e]; d = ei[E + e]; }
        else       { s = e - E; d = e - E; }
        const int b = d >> SHIFT;
        const int r = atomicAdd(&cnt[b], 1);
        E2[base[b] + r] = make_uint2((unsigned)s, (unsigned)d);
    }
}

__global__ __launch_bounds__(256) void k_bcsr(const uint2* __restrict__ E2,
                                              const int* __restrict__ BB, int N,
                                              int* __restrict__ deg,
                                              int* __restrict__ rowp,
                                              int* __restrict__ csr) {
    __shared__ int cnt[256];
    __shared__ int sc[256];
    __shared__ int rp[256];
    __shared__ int fl[256];
    const int t = threadIdx.x;
    const int b = blockIdx.x;
    const int lo = BB[b], hi = BB[b + 1];
    const int base_d = b << SHIFT;
    cnt[t] = 0; fl[t] = 0;
    __syncthreads();
    for (int i = lo + t; i < hi; i += 256)
        atomicAdd(&cnt[E2[i].y & 255], 1);
    __syncthreads();
    const int v = cnt[t];
    sc[t] = v;
    __syncthreads();
    for (int off = 1; off < 256; off <<= 1) {
        int add = (t >= off) ? sc[t - off] : 0;
        __syncthreads();
        sc[t] += add;
        __syncthreads();
    }
    rp[t] = sc[t] - v;
    const int d = base_d + t;
    if (d < N) { deg[d] = v; rowp[d] = lo + rp[t]; }
    __syncthreads();
    for (int i = lo + t; i < hi; i += 256) {
        const uint2 e = E2[i];
        const int ld = e.y & 255;
        const int r = atomicAdd(&fl[ld], 1);
        csr[lo + rp[ld] + r] = (int)e.x;
    }
}

// -------- layer-1 aggregate: 8-edge tiles, 2-phase (parallel attn + gather) ----
// lane = (head hA = lane>>3, edge-slot eA = lane&7). Phase A computes 8x8
// (edge,head) attn weights in parallel; phase B broadcasts via ds_swizzle.
__global__ __launch_bounds__(256) void k_l1(const unsigned short* __restrict__ xhb,
                                            const float* __restrict__ es,
                                            const float* __restrict__ ed,
                                            const int* __restrict__ rowp,
                                            const int* __restrict__ deg,
                                            const int* __restrict__ csr,
                                            const float* __restrict__ b1,
                                            float* __restrict__ hout, int N) {
    const int wave = threadIdx.x >> 6;
    const int lane = threadIdx.x & 63;
    const int n = blockIdx.x * 4 + wave;
    if (n >= N) return;
    const int hA = lane >> 3;        // this lane's head (both phases)
    const int eA = lane & 7;         // this lane's edge slot in phase A
    const float edv = ed[n * 8 + hA];
    const int start = rowp[n];
    const int cnt = deg[n];
    const int last = cnt - 1;        // cnt >= 1 always (self-loop)
    const int lane4 = lane * 4;      // byte offset of this lane's channel pair

    float acc0 = 0.f, acc1 = 0.f, dpart = 0.f;
    const char* xb = (const char*)xhb;

    for (int k = 0; k < cnt; k += 8) {
        // ---- phase A: 8 edges x 8 heads in parallel ----
        const int ke = k + eA;
        const int idx = start + min(ke, last);
        const int s = csr[idx];
        float a = lrelu_exp(es[s * 8 + hA] + edv);
        a = (ke <= last) ? a : 0.f;
        dpart += a;
        const int soff = s << 8;     // byte offset of row s in xhb (256 B/row)
        // ---- phase B: per edge e, broadcast (a, soff) from owning lane ----
#define L1E(e) { \
        const float ae = swz_f<SWZ(e)>(a); \
        const int   ro = swz_i<SWZ(e)>(soff); \
        const unsigned pv = *(const unsigned*)(xb + (unsigned)(ro + lane4)); \
        acc0 += ae * __uint_as_float(pv << 16); \
        acc1 += ae * __uint_as_float(pv & 0xffff0000u); }
        L1E(0) L1E(1) L1E(2) L1E(3) L1E(4) L1E(5) L1E(6) L1E(7)
#undef L1E
    }
    // dsum: reduce edge-slot partials within each head group (lands in hA layout)
    dpart += __shfl_xor(dpart, 1, 64);
    dpart += __shfl_xor(dpart, 2, 64);
    dpart += __shfl_xor(dpart, 4, 64);

    const float inv = 1.f / (dpart + EPSF);
    const float2 bb = *(const float2*)(b1 + lane * 2);
    float o0 = acc0 * inv + bb.x;
    float o1 = acc1 * inv + bb.y;
    o0 = (o0 > 0.f) ? o0 : expm1f(o0);
    o1 = (o1 > 0.f) ? o1 : expm1f(o1);
    *(float2*)(hout + (size_t)n * 128 + lane * 2) = make_float2(o0, o1);
}

// ------ GEMM2: xh2 = h @ W2 (N x 128)(128 x 40), fused e_src2/e_dst2 ---------
__global__ __launch_bounds__(256) void k_gemm2(const float* __restrict__ h,
                                               const float* __restrict__ W2,
                                               const float* __restrict__ as2,
                                               const float* __restrict__ ad2,
                                               float* __restrict__ xh2,
                                               float* __restrict__ es2,
                                               float* __restrict__ ed2, int N) {
    __shared__ float w[128 * 40];
    __shared__ float sa[40], sb[40];
    for (int i = threadIdx.x; i < 128 * 40 / 4; i += 256)
        ((float4*)w)[i] = ((const float4*)W2)[i];
    if (threadIdx.x < 40) { sa[threadIdx.x] = as2[threadIdx.x]; sb[threadIdx.x] = ad2[threadIdx.x]; }
    __syncthreads();
    const int n = blockIdx.x * 256 + threadIdx.x;
    if (n >= N) return;
    float acc[40];
    #pragma unroll
    for (int j = 0; j < 40; ++j) acc[j] = 0.f;
    const float4* hr = (const float4*)(h + (size_t)n * 128);
    for (int k4 = 0; k4 < 32; ++k4) {
        const float4 hv = hr[k4];
        const float hx[4] = {hv.x, hv.y, hv.z, hv.w};
        #pragma unroll
        for (int kk = 0; kk < 4; ++kk) {
            const float* wr = &w[(k4 * 4 + kk) * 40];
            #pragma unroll
            for (int j = 0; j < 40; j += 4) {
                const float4 wv = *(const float4*)&wr[j];
                acc[j]     += hx[kk] * wv.x;
                acc[j + 1] += hx[kk] * wv.y;
                acc[j + 2] += hx[kk] * wv.z;
                acc[j + 3] += hx[kk] * wv.w;
            }
        }
    }
    float4* op = (float4*)(xh2 + (size_t)n * 40);
    float s = 0.f, d = 0.f;
    #pragma unroll
    for (int j = 0; j < 10; ++j) {
        op[j] = make_float4(acc[4 * j], acc[4 * j + 1], acc[4 * j + 2], acc[4 * j + 3]);
        #pragma unroll
        for (int q = 0; q < 4; ++q) {
            s += acc[4 * j + q] * sa[4 * j + q];
            d += acc[4 * j + q] * sb[4 * j + q];
        }
    }
    es2[n] = s; ed2[n] = d;
}

// -------- layer-2 aggregate: 8-edge tiles, 2-phase, lane = class channel -------
__global__ __launch_bounds__(256) void k_l2(const float* __restrict__ xh2,
                                            const float* __restrict__ es2,
                                            const float* __restrict__ ed2,
                                            const int* __restrict__ rowp,
                                            const int* __restrict__ deg,
                                            const int* __restrict__ csr,
                                            const float* __restrict__ b2,
                                            float* __restrict__ out, int N) {
    const int wave = threadIdx.x >> 6;
    const int lane = threadIdx.x & 63;
    const int n = blockIdx.x * 4 + wave;
    if (n >= N) return;
    const float edv = ed2[n];
    const int start = rowp[n];
    const int cnt = deg[n];
    const int last = cnt - 1;
    const int eA = lane & 7;
    const int l4 = ((lane < 40) ? lane : 39) * 4;   // clamped channel byte offset
    const char* xb = (const char*)xh2;

    float acc = 0.f, dpart = 0.f;
    for (int k = 0; k < cnt; k += 8) {
        const int ke = k + eA;
        const int idx = start + min(ke, last);
        const int s = csr[idx];
        float a = lrelu_exp(es2[s] + edv);
        a = (ke <= last) ? a : 0.f;
        dpart += a;
        const int soff = s * 160;    // byte offset of row s in xh2 (160 B/row)
#define L2E(e) { \
        const float ae = swz_f<SWZ(e)>(a); \
        const int   ro = swz_i<SWZ(e)>(soff); \
        const float v = *(const float*)(xb + (unsigned)(ro + l4)); \
        acc += ae * v; }
        L2E(0) L2E(1) L2E(2) L2E(3) L2E(4) L2E(5) L2E(6) L2E(7)
#undef L2E
    }
    dpart += __shfl_xor(dpart, 1, 64);
    dpart += __shfl_xor(dpart, 2, 64);
    dpart += __shfl_xor(dpart, 4, 64);

    if (lane < 40)
        out[(size_t)n * 40 + lane] = acc / (dpart + EPSF) + b2[lane];
}

extern "C" void kernel_launch(void* const* d_in, const int* in_sizes, int n_in,
                              void* d_out, int out_size, void* d_ws, size_t ws_size,
                              hipStream_t stream) {
    const float* x   = (const float*)d_in[0];
    const int*   ei  = (const int*)d_in[1];
    const float* W1  = (const float*)d_in[2];
    const float* as1 = (const float*)d_in[3];
    const float* ad1 = (const float*)d_in[4];
    const float* b1  = (const float*)d_in[5];
    const float* W2  = (const float*)d_in[6];
    const float* as2 = (const float*)d_in[7];
    const float* ad2 = (const float*)d_in[8];
    const float* b2  = (const float*)d_in[9];
    float* out = (float*)d_out;

    const int N   = in_sizes[0] / 128;
    const int E   = in_sizes[1] / 2;
    const int Et  = E + N;
    const int NBK = (N + 255) >> SHIFT;

    // ---- workspace layout (~108 MB) ----
    char* p = (char*)d_ws;
    unsigned short* xhb = (unsigned short*)p; p += (size_t)N * 128 * 2;
    float* es1  = (float*)p; p += (size_t)N * 8 * 4;
    float* ed1  = (float*)p; p += (size_t)N * 8 * 4;
    int*   deg  = (int*)p;   p += (size_t)N * 4;
    int*   rowp = (int*)p;   p += (size_t)N * 4;
    int*   csr  = (int*)p;   p += (size_t)Et * 4;
    int*   H    = (int*)p;   p += (size_t)512 * ABLK * 4;
    int*   BT   = (int*)p;   p += 512 * 4;
    int*   BB   = (int*)p;   p += 512 * 4;
    float* hbuf = (float*)p; p += (size_t)N * 128 * 4;
    float* xh2  = (float*)p; p += (size_t)N * 40 * 4;
    uint2* E2 = (uint2*)hbuf;   // dead after k_bcsr; hbuf written first by k_l1
    float* es2 = es1;
    float* ed2 = ed1;

    k_gemm1 <<<(N + 31) / 32,   256, 0, stream>>>(x, W1, as1, ad1, xhb, es1, ed1, N);
    k_bhist <<<ABLK,            256, 0, stream>>>(ei, E, N, NBK, H);
    k_scanH <<<NBK,             512, 0, stream>>>(H, BT);
    k_scanBT<<<1,               512, 0, stream>>>(BT, BB, NBK);
    k_bscat <<<ABLK,            256, 0, stream>>>(ei, E, N, NBK, H, BB, E2);
    k_bcsr  <<<NBK,             256, 0, stream>>>(E2, BB, N, deg, rowp, csr);
    k_l1    <<<(N + 3) / 4,     256, 0, stream>>>(xhb, es1, ed1, rowp, deg, csr, b1, hbuf, N);
    k_gemm2 <<<(N + 255) / 256, 256, 0, stream>>>(hbuf, W2, as2, ad2, xh2, es2, ed2, N);
    k_l2    <<<(N + 3) / 4,     256, 0, stream>>>(xh2, es2, ed2, rowp, deg, csr, b2, out, N);
}

// Round 8
// 271.931 us; speedup vs baseline: 2.2825x; 1.0324x over previous
//
#include <hip/hip_runtime.h>

#define NEG_SLOPE 0.2f
#define EPSF 1e-16f
#define ABLK 512
#define SHIFT 8
// ds_swizzle BitMode pattern: src_lane = (lane & 0x18) | e
#define SWZ(e) (((e) << 5) | 0x18)

__device__ __forceinline__ float lrelu_exp(float a) {
    a = (a > 0.f) ? a : NEG_SLOPE * a;
    return __expf(a);
}

__device__ __forceinline__ unsigned short f2bf(float f) {   // RNE
    unsigned u = __float_as_uint(f);
    u += 0x7fff + ((u >> 16) & 1);
    return (unsigned short)(u >> 16);
}

__device__ __forceinline__ float bf_lo(unsigned pv) { return __uint_as_float(pv << 16); }
__device__ __forceinline__ float bf_hi(unsigned pv) { return __uint_as_float(pv & 0xffff0000u); }

template <int PAT>
__device__ __forceinline__ float swz_f(float v) {
    return __uint_as_float((unsigned)__builtin_amdgcn_ds_swizzle(__float_as_int(v), PAT));
}
template <int PAT>
__device__ __forceinline__ int swz_i(int v) {
    return __builtin_amdgcn_ds_swizzle(v, PAT);
}

// -- fused: GEMM1 (blocks [0,GB1)) + bhist (blocks [GB1, GB1+ABLK)) ------------
// GEMM1: xh1 = x @ W1 -> bf16, fused e_src1/e_dst1.  bhist: coarse histogram.
__global__ __launch_bounds__(256) void k_g1h(const float* __restrict__ x,
                                             const float* __restrict__ W,
                                             const float* __restrict__ asrc,
                                             const float* __restrict__ adst,
                                             unsigned short* __restrict__ xhb,
                                             float* __restrict__ es,
                                             float* __restrict__ ed, int N, int GB1,
                                             const int* __restrict__ ei, int E,
                                             int NBK, int* __restrict__ H) {
    __shared__ float xs[32][132];
    __shared__ float wsh[32][128];
    __shared__ int hist[512];
    const int t = threadIdx.x;

    if (blockIdx.x >= GB1) {
        // ---------------- bhist body ----------------
        const int hb = blockIdx.x - GB1;
        for (int i = t; i < NBK; i += 256) hist[i] = 0;
        __syncthreads();
        const int Et = E + N;
        for (int e = hb * 256 + t; e < Et; e += ABLK * 256) {
            int d = (e < E) ? ei[E + e] : (e - E);
            atomicAdd(&hist[d >> SHIFT], 1);
        }
        __syncthreads();
        for (int i = t; i < NBK; i += 256)
            H[(size_t)i * ABLK + hb] = hist[i];
        return;
    }

    // ---------------- gemm1 body ----------------
    const int row0 = blockIdx.x * 32;
    for (int i = t; i < 32 * 32; i += 256) {
        int r = i >> 5, c4 = i & 31;
        float4 v = make_float4(0.f, 0.f, 0.f, 0.f);
        if (row0 + r < N) v = ((const float4*)(x + (size_t)(row0 + r) * 128))[c4];
        *(float4*)&xs[r][c4 * 4] = v;
    }

    const int r0 = (t >> 5) * 4;
    const int c0 = (t & 31) * 4;
    float acc[4][4] = {};

    for (int kp = 0; kp < 128; kp += 32) {
        __syncthreads();
        for (int i = t; i < 32 * 32; i += 256) {
            int kr = i >> 5, c4 = i & 31;
            ((float4*)&wsh[kr][0])[c4] =
                ((const float4*)(W + (size_t)(kp + kr) * 128))[c4];
        }
        __syncthreads();
        #pragma unroll
        for (int kk = 0; kk < 32; ++kk) {
            const float4 wv = *(const float4*)&wsh[kk][c0];
            const int k = kp + kk;
            #pragma unroll
            for (int i = 0; i < 4; ++i) {
                const float xv = xs[r0 + i][k];
                acc[i][0] += xv * wv.x;
                acc[i][1] += xv * wv.y;
                acc[i][2] += xv * wv.z;
                acc[i][3] += xv * wv.w;
            }
        }
    }

    #pragma unroll
    for (int i = 0; i < 4; ++i) {
        const int row = row0 + r0 + i;
        if (row < N) {
            ushort4 pk;
            pk.x = f2bf(acc[i][0]);
            pk.y = f2bf(acc[i][1]);
            pk.z = f2bf(acc[i][2]);
            pk.w = f2bf(acc[i][3]);
            *(ushort4*)(xhb + (size_t)row * 128 + c0) = pk;
        }
    }

    const int head = c0 >> 4;
    const int cb   = c0 & 15;
    float4 av = *(const float4*)(asrc + head * 16 + cb);
    float4 bv = *(const float4*)(adst + head * 16 + cb);
    #pragma unroll
    for (int i = 0; i < 4; ++i) {
        float ps = acc[i][0] * av.x + acc[i][1] * av.y + acc[i][2] * av.z + acc[i][3] * av.w;
        float pd = acc[i][0] * bv.x + acc[i][1] * bv.y + acc[i][2] * bv.z + acc[i][3] * bv.w;
        ps += __shfl_xor(ps, 1, 64); ps += __shfl_xor(ps, 2, 64);
        pd += __shfl_xor(pd, 1, 64); pd += __shfl_xor(pd, 2, 64);
        const int row = row0 + r0 + i;
        if ((t & 3) == 0 && row < N) {
            es[row * 8 + head] = ps;
            ed[row * 8 + head] = pd;
        }
    }
}

__global__ __launch_bounds__(512) void k_scanH(int* __restrict__ H, int* __restrict__ BT) {
    __shared__ int sd[512];
    const int t = threadIdx.x;
    int* row = H + (size_t)blockIdx.x * ABLK;
    const int v = row[t];
    sd[t] = v;
    __syncthreads();
    for (int off = 1; off < 512; off <<= 1) {
        int add = (t >= off) ? sd[t - off] : 0;
        __syncthreads();
        sd[t] += add;
        __syncthreads();
    }
    row[t] = sd[t] - v;
    if (t == 511) BT[blockIdx.x] = sd[511];
}

__global__ __launch_bounds__(512) void k_scanBT(const int* __restrict__ BT,
                                                int* __restrict__ BB, int NBK) {
    __shared__ int sd[512];
    const int t = threadIdx.x;
    const int v = (t < NBK) ? BT[t] : 0;
    sd[t] = v;
    __syncthreads();
    for (int off = 1; off < 512; off <<= 1) {
        int add = (t >= off) ? sd[t - off] : 0;
        __syncthreads();
        sd[t] += add;
        __syncthreads();
    }
    if (t < NBK) BB[t] = sd[t] - v;
    if (t == 511) BB[NBK] = sd[511];
}

__global__ __launch_bounds__(256) void k_bscat(const int* __restrict__ ei, int E, int N,
                                               int NBK, const int* __restrict__ H,
                                               const int* __restrict__ BB,
                                               uint2* __restrict__ E2) {
    __shared__ int cnt[512];
    __shared__ int base[512];
    const int t = threadIdx.x;
    for (int i = t; i < NBK; i += 256) {
        cnt[i] = 0;
        base[i] = BB[i] + H[(size_t)i * ABLK + blockIdx.x];
    }
    __syncthreads();
    const int Et = E + N;
    for (int e = blockIdx.x * 256 + t; e < Et; e += ABLK * 256) {
        int s, d;
        if (e < E) { s = ei[e]; d = ei[E + e]; }
        else       { s = e - E; d = e - E; }
        const int b = d >> SHIFT;
        const int r = atomicAdd(&cnt[b], 1);
        E2[base[b] + r] = make_uint2((unsigned)s, (unsigned)d);
    }
}

__global__ __launch_bounds__(256) void k_bcsr(const uint2* __restrict__ E2,
                                              const int* __restrict__ BB, int N,
                                              int* __restrict__ deg,
                                              int* __restrict__ rowp,
                                              int* __restrict__ csr) {
    __shared__ int cnt[256];
    __shared__ int sc[256];
    __shared__ int rp[256];
    __shared__ int fl[256];
    const int t = threadIdx.x;
    const int b = blockIdx.x;
    const int lo = BB[b], hi = BB[b + 1];
    const int base_d = b << SHIFT;
    cnt[t] = 0; fl[t] = 0;
    __syncthreads();
    for (int i = lo + t; i < hi; i += 256)
        atomicAdd(&cnt[E2[i].y & 255], 1);
    __syncthreads();
    const int v = cnt[t];
    sc[t] = v;
    __syncthreads();
    for (int off = 1; off < 256; off <<= 1) {
        int add = (t >= off) ? sc[t - off] : 0;
        __syncthreads();
        sc[t] += add;
        __syncthreads();
    }
    rp[t] = sc[t] - v;
    const int d = base_d + t;
    if (d < N) { deg[d] = v; rowp[d] = lo + rp[t]; }
    __syncthreads();
    for (int i = lo + t; i < hi; i += 256) {
        const uint2 e = E2[i];
        const int ld = e.y & 255;
        const int r = atomicAdd(&fl[ld], 1);
        csr[lo + rp[ld] + r] = (int)e.x;
    }
}

// -------- layer-1 aggregate: 8-edge tiles, 2-phase; h written as bf16 ----------
__global__ __launch_bounds__(256) void k_l1(const unsigned short* __restrict__ xhb,
                                            const float* __restrict__ es,
                                            const float* __restrict__ ed,
                                            const int* __restrict__ rowp,
                                            const int* __restrict__ deg,
                                            const int* __restrict__ csr,
                                            const float* __restrict__ b1,
                                            unsigned short* __restrict__ hb, int N) {
    const int wave = threadIdx.x >> 6;
    const int lane = threadIdx.x & 63;
    const int n = blockIdx.x * 4 + wave;
    if (n >= N) return;
    const int hA = lane >> 3;
    const int eA = lane & 7;
    const float edv = ed[n * 8 + hA];
    const int start = rowp[n];
    const int cnt = deg[n];
    const int last = cnt - 1;
    const int lane4 = lane * 4;

    float acc0 = 0.f, acc1 = 0.f, dpart = 0.f;
    const char* xb = (const char*)xhb;

    for (int k = 0; k < cnt; k += 8) {
        const int ke = k + eA;
        const int idx = start + min(ke, last);
        const int s = csr[idx];
        float a = lrelu_exp(es[s * 8 + hA] + edv);
        a = (ke <= last) ? a : 0.f;
        dpart += a;
        const int soff = s << 8;
#define L1E(e) { \
        const float ae = swz_f<SWZ(e)>(a); \
        const int   ro = swz_i<SWZ(e)>(soff); \
        const unsigned pv = *(const unsigned*)(xb + (unsigned)(ro + lane4)); \
        acc0 += ae * bf_lo(pv); \
        acc1 += ae * bf_hi(pv); }
        L1E(0) L1E(1) L1E(2) L1E(3) L1E(4) L1E(5) L1E(6) L1E(7)
#undef L1E
    }
    dpart += __shfl_xor(dpart, 1, 64);
    dpart += __shfl_xor(dpart, 2, 64);
    dpart += __shfl_xor(dpart, 4, 64);

    const float inv = 1.f / (dpart + EPSF);
    const float2 bb = *(const float2*)(b1 + lane * 2);
    float o0 = acc0 * inv + bb.x;
    float o1 = acc1 * inv + bb.y;
    o0 = (o0 > 0.f) ? o0 : expm1f(o0);
    o1 = (o1 > 0.f) ? o1 : expm1f(o1);
    const unsigned pk = (unsigned)f2bf(o0) | ((unsigned)f2bf(o1) << 16);
    *(unsigned*)(hb + (size_t)n * 128 + lane * 2) = pk;
}

// ---- GEMM2: xh2 = h @ W2 -> bf16 rows padded to 128 B, fused e_src2/e_dst2 ----
__global__ __launch_bounds__(256) void k_gemm2(const unsigned short* __restrict__ h,
                                               const float* __restrict__ W2,
                                               const float* __restrict__ as2,
                                               const float* __restrict__ ad2,
                                               unsigned short* __restrict__ xh2,
                                               float* __restrict__ es2,
                                               float* __restrict__ ed2, int N) {
    __shared__ float w[128 * 40];
    __shared__ float sa[40], sb[40];
    for (int i = threadIdx.x; i < 128 * 40 / 4; i += 256)
        ((float4*)w)[i] = ((const float4*)W2)[i];
    if (threadIdx.x < 40) { sa[threadIdx.x] = as2[threadIdx.x]; sb[threadIdx.x] = ad2[threadIdx.x]; }
    __syncthreads();
    const int n = blockIdx.x * 256 + threadIdx.x;
    if (n >= N) return;
    float acc[40];
    #pragma unroll
    for (int j = 0; j < 40; ++j) acc[j] = 0.f;
    const uint4* hr = (const uint4*)(h + (size_t)n * 128);
    for (int k8 = 0; k8 < 16; ++k8) {
        const uint4 hv = hr[k8];
        float hx[8];
        hx[0] = bf_lo(hv.x); hx[1] = bf_hi(hv.x);
        hx[2] = bf_lo(hv.y); hx[3] = bf_hi(hv.y);
        hx[4] = bf_lo(hv.z); hx[5] = bf_hi(hv.z);
        hx[6] = bf_lo(hv.w); hx[7] = bf_hi(hv.w);
        #pragma unroll
        for (int kk = 0; kk < 8; ++kk) {
            const float* wr = &w[(k8 * 8 + kk) * 40];
            #pragma unroll
            for (int j = 0; j < 40; j += 4) {
                const float4 wv = *(const float4*)&wr[j];
                acc[j]     += hx[kk] * wv.x;
                acc[j + 1] += hx[kk] * wv.y;
                acc[j + 2] += hx[kk] * wv.z;
                acc[j + 3] += hx[kk] * wv.w;
            }
        }
    }
    // pack 40 bf16 (20 u32 = 5 uint4) into padded row of 64 ushorts
    uint4* op = (uint4*)(xh2 + (size_t)n * 64);
    float s = 0.f, d = 0.f;
    #pragma unroll
    for (int q = 0; q < 5; ++q) {
        uint4 pk;
        pk.x = (unsigned)f2bf(acc[8 * q])     | ((unsigned)f2bf(acc[8 * q + 1]) << 16);
        pk.y = (unsigned)f2bf(acc[8 * q + 2]) | ((unsigned)f2bf(acc[8 * q + 3]) << 16);
        pk.z = (unsigned)f2bf(acc[8 * q + 4]) | ((unsigned)f2bf(acc[8 * q + 5]) << 16);
        pk.w = (unsigned)f2bf(acc[8 * q + 6]) | ((unsigned)f2bf(acc[8 * q + 7]) << 16);
        op[q] = pk;
    }
    #pragma unroll
    for (int j = 0; j < 40; ++j) {
        s += acc[j] * sa[j];
        d += acc[j] * sb[j];
    }
    es2[n] = s; ed2[n] = d;
}

// ---- layer-2 aggregate: 8-edge tiles, 2-phase; bf16 rows, 20 active lanes -----
__global__ __launch_bounds__(256) void k_l2(const unsigned short* __restrict__ xh2,
                                            const float* __restrict__ es2,
                                            const float* __restrict__ ed2,
                                            const int* __restrict__ rowp,
                                            const int* __restrict__ deg,
                                            const int* __restrict__ csr,
                                            const float* __restrict__ b2,
                                            float* __restrict__ out, int N) {
    const int wave = threadIdx.x >> 6;
    const int lane = threadIdx.x & 63;
    const int n = blockIdx.x * 4 + wave;
    if (n >= N) return;
    const float edv = ed2[n];
    const int start = rowp[n];
    const int cnt = deg[n];
    const int last = cnt - 1;
    const int eA = lane & 7;
    const int cc4 = ((lane < 20) ? lane : 19) * 4;   // clamped u32 byte offset
    const char* xb = (const char*)xh2;

    float acc0 = 0.f, acc1 = 0.f, dpart = 0.f;
    for (int k = 0; k < cnt; k += 8) {
        const int ke = k + eA;
        const int idx = start + min(ke, last);
        const int s = csr[idx];
        float a = lrelu_exp(es2[s] + edv);
        a = (ke <= last) ? a : 0.f;
        dpart += a;
        const int soff = s << 7;     // 128-B padded bf16 rows
#define L2E(e) { \
        const float ae = swz_f<SWZ(e)>(a); \
        const int   ro = swz_i<SWZ(e)>(soff); \
        const unsigned pv = *(const unsigned*)(xb + (unsigned)(ro + cc4)); \
        acc0 += ae * bf_lo(pv); \
        acc1 += ae * bf_hi(pv); }
        L2E(0) L2E(1) L2E(2) L2E(3) L2E(4) L2E(5) L2E(6) L2E(7)
#undef L2E
    }
    dpart += __shfl_xor(dpart, 1, 64);
    dpart += __shfl_xor(dpart, 2, 64);
    dpart += __shfl_xor(dpart, 4, 64);

    if (lane < 20) {
        const float inv = 1.f / (dpart + EPSF);
        const float2 bb = *(const float2*)(b2 + lane * 2);
        *(float2*)(out + (size_t)n * 40 + lane * 2) =
            make_float2(acc0 * inv + bb.x, acc1 * inv + bb.y);
    }
}

extern "C" void kernel_launch(void* const* d_in, const int* in_sizes, int n_in,
                              void* d_out, int out_size, void* d_ws, size_t ws_size,
                              hipStream_t stream) {
    const float* x   = (const float*)d_in[0];
    const int*   ei  = (const int*)d_in[1];
    const float* W1  = (const float*)d_in[2];
    const float* as1 = (const float*)d_in[3];
    const float* ad1 = (const float*)d_in[4];
    const float* b1  = (const float*)d_in[5];
    const float* W2  = (const float*)d_in[6];
    const float* as2 = (const float*)d_in[7];
    const float* ad2 = (const float*)d_in[8];
    const float* b2  = (const float*)d_in[9];
    float* out = (float*)d_out;

    const int N   = in_sizes[0] / 128;
    const int E   = in_sizes[1] / 2;
    const int Et  = E + N;
    const int NBK = (N + 255) >> SHIFT;
    const int GB1 = (N + 31) / 32;

    // ---- workspace layout (~80 MB) ----
    char* p = (char*)d_ws;
    unsigned short* xhb = (unsigned short*)p; p += (size_t)N * 128 * 2;
    float* es1  = (float*)p; p += (size_t)N * 8 * 4;
    float* ed1  = (float*)p; p += (size_t)N * 8 * 4;
    int*   deg  = (int*)p;   p += (size_t)N * 4;
    int*   rowp = (int*)p;   p += (size_t)N * 4;
    int*   csr  = (int*)p;   p += (size_t)Et * 4;
    int*   H    = (int*)p;   p += (size_t)512 * ABLK * 4;
    int*   BT   = (int*)p;   p += 512 * 4;
    int*   BB   = (int*)p;   p += 512 * 4;
    unsigned short* hbuf = (unsigned short*)p; p += (size_t)N * 128 * 2;
    unsigned short* xh2  = (unsigned short*)p; p += (size_t)N * 64 * 2;
    uint2* E2 = (uint2*)hbuf;   // 13.6 MB < 25.6 MB; dead after k_bcsr
    float* es2 = es1;
    float* ed2 = ed1;

    k_g1h   <<<GB1 + ABLK,      256, 0, stream>>>(x, W1, as1, ad1, xhb, es1, ed1, N, GB1,
                                                  ei, E, NBK, H);
    k_scanH <<<NBK,             512, 0, stream>>>(H, BT);
    k_scanBT<<<1,               512, 0, stream>>>(BT, BB, NBK);
    k_bscat <<<ABLK,            256, 0, stream>>>(ei, E, N, NBK, H, BB, E2);
    k_bcsr  <<<NBK,             256, 0, stream>>>(E2, BB, N, deg, rowp, csr);
    k_l1    <<<(N + 3) / 4,     256, 0, stream>>>(xhb, es1, ed1, rowp, deg, csr, b1, hbuf, N);
    k_gemm2 <<<(N + 255) / 256, 256, 0, stream>>>(hbuf, W2, as2, ad2, xh2, es2, ed2, N);
    k_l2    <<<(N + 3) / 4,     256, 0, stream>>>(xh2, es2, ed2, rowp, deg, csr, b2, out, N);
}

// Round 9
// 237.900 us; speedup vs baseline: 2.6090x; 1.1430x over previous
//
#include <hip/hip_runtime.h>

#define NEG_SLOPE 0.2f
#define EPSF 1e-16f
#define ABLK 512
#define SHIFT 8
#define SWZ(e) (((e) << 5) | 0x18)

using short8 = __attribute__((ext_vector_type(8))) short;
using f32x4  = __attribute__((ext_vector_type(4))) float;

__device__ __forceinline__ float lrelu_exp(float a) {
    a = (a > 0.f) ? a : NEG_SLOPE * a;
    return __expf(a);
}

__device__ __forceinline__ unsigned short f2bf(float f) {   // RNE
    unsigned u = __float_as_uint(f);
    u += 0x7fff + ((u >> 16) & 1);
    return (unsigned short)(u >> 16);
}

__device__ __forceinline__ float bf2f(unsigned short b) {
    return __uint_as_float(((unsigned)b) << 16);
}

__device__ __forceinline__ float bf_lo(unsigned pv) { return __uint_as_float(pv << 16); }
__device__ __forceinline__ float bf_hi(unsigned pv) { return __uint_as_float(pv & 0xffff0000u); }

template <int PAT>
__device__ __forceinline__ float swz_f(float v) {
    return __uint_as_float((unsigned)__builtin_amdgcn_ds_swizzle(__float_as_int(v), PAT));
}
template <int PAT>
__device__ __forceinline__ int swz_i(int v) {
    return __builtin_amdgcn_ds_swizzle(v, PAT);
}

// ---- prep: pre-swizzle W1 (128x128) and W2 (128x40 pad 48) into MFMA
// fragment-linear bf16 hi/lo buffers. frag: lane l holds k=(kt*32+(l>>4)*8+e),
// n = nt*16 + (l&15); ushort idx = frag*512 + l*8 + e.
__global__ __launch_bounds__(256) void k_prep(const float* __restrict__ W1,
                                              const float* __restrict__ W2,
                                              unsigned short* __restrict__ W1s,
                                              unsigned short* __restrict__ W2s) {
    const int tid = blockIdx.x * 256 + threadIdx.x;
    if (tid < 16384) {                       // W1: 4kt x 8nt x 64l x 8e
        const int e  = tid & 7;
        const int l  = (tid >> 3) & 63;
        const int nt = (tid >> 9) & 7;
        const int kt = tid >> 12;
        const int k  = kt * 32 + ((l >> 4) * 8) + e;
        const int n  = nt * 16 + (l & 15);
        const float w = W1[k * 128 + n];
        const unsigned short hi = f2bf(w);
        const unsigned short lo = f2bf(w - bf2f(hi));
        const int idx = (kt * 8 + nt) * 512 + l * 8 + e;
        W1s[idx] = hi;
        W1s[16384 + idx] = lo;
    } else {                                 // W2: 4kt x 3nt x 64l x 8e
        const int t2 = tid - 16384;
        if (t2 >= 6144) return;
        const int e  = t2 & 7;
        const int l  = (t2 >> 3) & 63;
        const int g  = t2 >> 9;              // 0..11
        const int nt = g % 3;
        const int kt = g / 3;
        const int k  = kt * 32 + ((l >> 4) * 8) + e;
        const int n  = nt * 16 + (l & 15);
        const float w = (n < 40) ? W2[k * 40 + n] : 0.f;
        const unsigned short hi = f2bf(w);
        const unsigned short lo = f2bf(w - bf2f(hi));
        const int idx = (kt * 3 + nt) * 512 + l * 8 + e;
        W2s[idx] = hi;
        W2s[6144 + idx] = lo;
    }
}

// ---- GEMM1 (MFMA bf16x3): xh1 = x @ W1 -> bf16. Block = 64 rows, 4 waves. ----
__global__ __launch_bounds__(256) void k_mm1(const float* __restrict__ x,
                                             const unsigned short* __restrict__ W1s,
                                             unsigned short* __restrict__ xhb, int N) {
    __shared__ unsigned short Bs[32768];     // 64 KB: hi frags then lo frags
    const int t = threadIdx.x;
    for (int i = t; i < 4096; i += 256)
        ((uint4*)Bs)[i] = ((const uint4*)W1s)[i];

    const int wm = t >> 6;
    const int l  = t & 63;
    const int wrow0 = blockIdx.x * 64 + wm * 16;
    const int arow = wrow0 + (l & 15);
    const int rc = (arow < N) ? arow : (N - 1);

    short8 ah[4], al[4];
    #pragma unroll
    for (int kt = 0; kt < 4; ++kt) {
        const float* xp = x + (size_t)rc * 128 + kt * 32 + ((l >> 4) * 8);
        const float4 v0 = ((const float4*)xp)[0];
        const float4 v1 = ((const float4*)xp)[1];
        const float vv[8] = {v0.x, v0.y, v0.z, v0.w, v1.x, v1.y, v1.z, v1.w};
        #pragma unroll
        for (int e = 0; e < 8; ++e) {
            const unsigned short hi = f2bf(vv[e]);
            ((unsigned short*)&ah[kt])[e] = hi;
            ((unsigned short*)&al[kt])[e] = f2bf(vv[e] - bf2f(hi));
        }
    }
    __syncthreads();

    f32x4 acc[8] = {};
    #pragma unroll
    for (int kt = 0; kt < 4; ++kt) {
        #pragma unroll
        for (int nt = 0; nt < 8; ++nt) {
            const short8 bh = *(const short8*)(Bs + (kt * 8 + nt) * 512 + l * 8);
            const short8 bl = *(const short8*)(Bs + 16384 + (kt * 8 + nt) * 512 + l * 8);
            acc[nt] = __builtin_amdgcn_mfma_f32_16x16x32_bf16(ah[kt], bh, acc[nt], 0, 0, 0);
            acc[nt] = __builtin_amdgcn_mfma_f32_16x16x32_bf16(ah[kt], bl, acc[nt], 0, 0, 0);
            acc[nt] = __builtin_amdgcn_mfma_f32_16x16x32_bf16(al[kt], bh, acc[nt], 0, 0, 0);
        }
    }

    // store: row = wrow0 + (l>>4)*4 + reg, col = nt*16 + (l&15)
    const int rbase = wrow0 + ((l >> 4) * 4);
    const int col = l & 15;
    #pragma unroll
    for (int reg = 0; reg < 4; ++reg) {
        const int orow = rbase + reg;
        if (orow < N) {
            #pragma unroll
            for (int nt = 0; nt < 8; ++nt)
                xhb[(size_t)orow * 128 + nt * 16 + col] = f2bf(acc[nt][reg]);
        }
    }
}

// ---- e_src1/e_dst1 from bf16 xh: thread = (node, head) -----------------------
__global__ __launch_bounds__(256) void k_esed1(const unsigned short* __restrict__ xhb,
                                               const float* __restrict__ asrc,
                                               const float* __restrict__ adst,
                                               float* __restrict__ es,
                                               float* __restrict__ ed, int N) {
    const int i = blockIdx.x * 256 + threadIdx.x;
    if (i >= N * 8) return;
    const int h = i & 7;
    const uint4* p = (const uint4*)(xhb + (size_t)i * 16);
    const uint4 q0 = p[0], q1 = p[1];
    const unsigned w[8] = {q0.x, q0.y, q0.z, q0.w, q1.x, q1.y, q1.z, q1.w};
    const float* av = asrc + h * 16;
    const float* bv = adst + h * 16;
    float s = 0.f, d = 0.f;
    #pragma unroll
    for (int j = 0; j < 8; ++j) {
        const float v0 = bf_lo(w[j]);
        const float v1 = bf_hi(w[j]);
        s += v0 * av[2 * j] + v1 * av[2 * j + 1];
        d += v0 * bv[2 * j] + v1 * bv[2 * j + 1];
    }
    es[i] = s; ed[i] = d;
}

// ---------- CSR build ----------------------------------------------------------
__global__ __launch_bounds__(256) void k_bhist(const int* __restrict__ ei, int E, int N,
                                               int NBK, int* __restrict__ H) {
    __shared__ int hist[512];
    const int t = threadIdx.x;
    for (int i = t; i < NBK; i += 256) hist[i] = 0;
    __syncthreads();
    const int Et = E + N;
    for (int e = blockIdx.x * 256 + t; e < Et; e += ABLK * 256) {
        int d = (e < E) ? ei[E + e] : (e - E);
        atomicAdd(&hist[d >> SHIFT], 1);
    }
    __syncthreads();
    for (int i = t; i < NBK; i += 256)
        H[(size_t)i * ABLK + blockIdx.x] = hist[i];
}

__global__ __launch_bounds__(512) void k_scanH(int* __restrict__ H, int* __restrict__ BT) {
    __shared__ int sd[512];
    const int t = threadIdx.x;
    int* row = H + (size_t)blockIdx.x * ABLK;
    const int v = row[t];
    sd[t] = v;
    __syncthreads();
    for (int off = 1; off < 512; off <<= 1) {
        int add = (t >= off) ? sd[t - off] : 0;
        __syncthreads();
        sd[t] += add;
        __syncthreads();
    }
    row[t] = sd[t] - v;
    if (t == 511) BT[blockIdx.x] = sd[511];
}

__global__ __launch_bounds__(512) void k_scanBT(const int* __restrict__ BT,
                                                int* __restrict__ BB, int NBK) {
    __shared__ int sd[512];
    const int t = threadIdx.x;
    const int v = (t < NBK) ? BT[t] : 0;
    sd[t] = v;
    __syncthreads();
    for (int off = 1; off < 512; off <<= 1) {
        int add = (t >= off) ? sd[t - off] : 0;
        __syncthreads();
        sd[t] += add;
        __syncthreads();
    }
    if (t < NBK) BB[t] = sd[t] - v;
    if (t == 511) BB[NBK] = sd[511];
}

// E2 packed u32: src | (dst&255)<<24   (src < 2^24)
__global__ __launch_bounds__(256) void k_bscat(const int* __restrict__ ei, int E, int N,
                                               int NBK, const int* __restrict__ H,
                                               const int* __restrict__ BB,
                                               unsigned* __restrict__ E2) {
    __shared__ int cnt[512];
    __shared__ int base[512];
    const int t = threadIdx.x;
    for (int i = t; i < NBK; i += 256) {
        cnt[i] = 0;
        base[i] = BB[i] + H[(size_t)i * ABLK + blockIdx.x];
    }
    __syncthreads();
    const int Et = E + N;
    for (int e = blockIdx.x * 256 + t; e < Et; e += ABLK * 256) {
        int s, d;
        if (e < E) { s = ei[e]; d = ei[E + e]; }
        else       { s = e - E; d = e - E; }
        const int b = d >> SHIFT;
        const int r = atomicAdd(&cnt[b], 1);
        E2[base[b] + r] = (unsigned)s | ((unsigned)(d & 255) << 24);
    }
}

__global__ __launch_bounds__(256) void k_bcsr(const unsigned* __restrict__ E2,
                                              const int* __restrict__ BB, int N,
                                              int* __restrict__ deg,
                                              int* __restrict__ rowp,
                                              int* __restrict__ csr) {
    __shared__ int cnt[256];
    __shared__ int sc[256];
    __shared__ int rp[256];
    __shared__ int fl[256];
    const int t = threadIdx.x;
    const int b = blockIdx.x;
    const int lo = BB[b], hi = BB[b + 1];
    const int base_d = b << SHIFT;
    cnt[t] = 0; fl[t] = 0;
    __syncthreads();
    for (int i = lo + t; i < hi; i += 256)
        atomicAdd(&cnt[E2[i] >> 24], 1);
    __syncthreads();
    const int v = cnt[t];
    sc[t] = v;
    __syncthreads();
    for (int off = 1; off < 256; off <<= 1) {
        int add = (t >= off) ? sc[t - off] : 0;
        __syncthreads();
        sc[t] += add;
        __syncthreads();
    }
    rp[t] = sc[t] - v;
    const int d = base_d + t;
    if (d < N) { deg[d] = v; rowp[d] = lo + rp[t]; }
    __syncthreads();
    for (int i = lo + t; i < hi; i += 256) {
        const unsigned e = E2[i];
        const int ld = e >> 24;
        const int r = atomicAdd(&fl[ld], 1);
        csr[lo + rp[ld] + r] = (int)(e & 0xFFFFFFu);
    }
}

// -------- layer-1 aggregate: 8-edge tiles, 2-phase; h written as bf16 ----------
__global__ __launch_bounds__(256) void k_l1(const unsigned short* __restrict__ xhb,
                                            const float* __restrict__ es,
                                            const float* __restrict__ ed,
                                            const int* __restrict__ rowp,
                                            const int* __restrict__ deg,
                                            const int* __restrict__ csr,
                                            const float* __restrict__ b1,
                                            unsigned short* __restrict__ hb, int N) {
    const int wave = threadIdx.x >> 6;
    const int lane = threadIdx.x & 63;
    const int n = blockIdx.x * 4 + wave;
    if (n >= N) return;
    const int hA = lane >> 3;
    const int eA = lane & 7;
    const float edv = ed[n * 8 + hA];
    const int start = rowp[n];
    const int cnt = deg[n];
    const int last = cnt - 1;
    const int lane4 = lane * 4;

    float acc0 = 0.f, acc1 = 0.f, dpart = 0.f;
    const char* xb = (const char*)xhb;

    for (int k = 0; k < cnt; k += 8) {
        const int ke = k + eA;
        const int idx = start + min(ke, last);
        const int s = csr[idx];
        float a = lrelu_exp(es[s * 8 + hA] + edv);
        a = (ke <= last) ? a : 0.f;
        dpart += a;
        const int soff = s << 8;
#define L1E(e) { \
        const float ae = swz_f<SWZ(e)>(a); \
        const int   ro = swz_i<SWZ(e)>(soff); \
        const unsigned pv = *(const unsigned*)(xb + (unsigned)(ro + lane4)); \
        acc0 += ae * bf_lo(pv); \
        acc1 += ae * bf_hi(pv); }
        L1E(0) L1E(1) L1E(2) L1E(3) L1E(4) L1E(5) L1E(6) L1E(7)
#undef L1E
    }
    dpart += __shfl_xor(dpart, 1, 64);
    dpart += __shfl_xor(dpart, 2, 64);
    dpart += __shfl_xor(dpart, 4, 64);

    const float inv = 1.f / (dpart + EPSF);
    const float2 bb = *(const float2*)(b1 + lane * 2);
    float o0 = acc0 * inv + bb.x;
    float o1 = acc1 * inv + bb.y;
    o0 = (o0 > 0.f) ? o0 : expm1f(o0);
    o1 = (o1 > 0.f) ? o1 : expm1f(o1);
    const unsigned pk = (unsigned)f2bf(o0) | ((unsigned)f2bf(o1) << 16);
    *(unsigned*)(hb + (size_t)n * 128 + lane * 2) = pk;
}

// ---- GEMM2 (MFMA): xh2 = h @ W2 -> bf16 rows padded to 64 ushorts -------------
__global__ __launch_bounds__(256) void k_mm2(const unsigned short* __restrict__ h,
                                             const unsigned short* __restrict__ W2s,
                                             unsigned short* __restrict__ xh2, int N) {
    __shared__ unsigned short Bs[12288];     // 24 KB
    const int t = threadIdx.x;
    for (int i = t; i < 1536; i += 256)
        ((uint4*)Bs)[i] = ((const uint4*)W2s)[i];

    const int wm = t >> 6;
    const int l  = t & 63;
    const int wrow0 = blockIdx.x * 64 + wm * 16;
    const int arow = wrow0 + (l & 15);
    const int rc = (arow < N) ? arow : (N - 1);

    short8 a[4];
    #pragma unroll
    for (int kt = 0; kt < 4; ++kt)
        a[kt] = *(const short8*)(h + (size_t)rc * 128 + kt * 32 + ((l >> 4) * 8));
    __syncthreads();

    f32x4 acc[3] = {};
    #pragma unroll
    for (int kt = 0; kt < 4; ++kt) {
        #pragma unroll
        for (int nt = 0; nt < 3; ++nt) {
            const short8 bh = *(const short8*)(Bs + (kt * 3 + nt) * 512 + l * 8);
            const short8 bl = *(const short8*)(Bs + 6144 + (kt * 3 + nt) * 512 + l * 8);
            acc[nt] = __builtin_amdgcn_mfma_f32_16x16x32_bf16(a[kt], bh, acc[nt], 0, 0, 0);
            acc[nt] = __builtin_amdgcn_mfma_f32_16x16x32_bf16(a[kt], bl, acc[nt], 0, 0, 0);
        }
    }

    const int rbase = wrow0 + ((l >> 4) * 4);
    const int col = l & 15;
    #pragma unroll
    for (int reg = 0; reg < 4; ++reg) {
        const int orow = rbase + reg;
        if (orow < N) {
            #pragma unroll
            for (int nt = 0; nt < 3; ++nt) {
                const int c = nt * 16 + col;
                if (c < 40)
                    xh2[(size_t)orow * 64 + c] = f2bf(acc[nt][reg]);
            }
        }
    }
}

// ---- e_src2/e_dst2 from bf16 xh2: thread = node -------------------------------
__global__ __launch_bounds__(256) void k_esed2(const unsigned short* __restrict__ xh2,
                                               const float* __restrict__ as2,
                                               const float* __restrict__ ad2,
                                               float* __restrict__ es2,
                                               float* __restrict__ ed2, int N) {
    const int n = blockIdx.x * 256 + threadIdx.x;
    if (n >= N) return;
    const unsigned* p = (const unsigned*)(xh2 + (size_t)n * 64);
    float s = 0.f, d = 0.f;
    #pragma unroll
    for (int j = 0; j < 20; ++j) {
        const unsigned w = p[j];
        const float v0 = bf_lo(w);
        const float v1 = bf_hi(w);
        s += v0 * as2[2 * j] + v1 * as2[2 * j + 1];
        d += v0 * ad2[2 * j] + v1 * ad2[2 * j + 1];
    }
    es2[n] = s; ed2[n] = d;
}

// ---- layer-2 aggregate: 8-edge tiles, 2-phase; bf16 rows, 20 active lanes -----
__global__ __launch_bounds__(256) void k_l2(const unsigned short* __restrict__ xh2,
                                            const float* __restrict__ es2,
                                            const float* __restrict__ ed2,
                                            const int* __restrict__ rowp,
                                            const int* __restrict__ deg,
                                            const int* __restrict__ csr,
                                            const float* __restrict__ b2,
                                            float* __restrict__ out, int N) {
    const int wave = threadIdx.x >> 6;
    const int lane = threadIdx.x & 63;
    const int n = blockIdx.x * 4 + wave;
    if (n >= N) return;
    const float edv = ed2[n];
    const int start = rowp[n];
    const int cnt = deg[n];
    const int last = cnt - 1;
    const int eA = lane & 7;
    const int cc4 = ((lane < 20) ? lane : 19) * 4;
    const char* xb = (const char*)xh2;

    float acc0 = 0.f, acc1 = 0.f, dpart = 0.f;
    for (int k = 0; k < cnt; k += 8) {
        const int ke = k + eA;
        const int idx = start + min(ke, last);
        const int s = csr[idx];
        float a = lrelu_exp(es2[s] + edv);
        a = (ke <= last) ? a : 0.f;
        dpart += a;
        const int soff = s << 7;
#define L2E(e) { \
        const float ae = swz_f<SWZ(e)>(a); \
        const int   ro = swz_i<SWZ(e)>(soff); \
        const unsigned pv = *(const unsigned*)(xb + (unsigned)(ro + cc4)); \
        acc0 += ae * bf_lo(pv); \
        acc1 += ae * bf_hi(pv); }
        L2E(0) L2E(1) L2E(2) L2E(3) L2E(4) L2E(5) L2E(6) L2E(7)
#undef L2E
    }
    dpart += __shfl_xor(dpart, 1, 64);
    dpart += __shfl_xor(dpart, 2, 64);
    dpart += __shfl_xor(dpart, 4, 64);

    if (lane < 20) {
        const float inv = 1.f / (dpart + EPSF);
        const float2 bb = *(const float2*)(b2 + lane * 2);
        *(float2*)(out + (size_t)n * 40 + lane * 2) =
            make_float2(acc0 * inv + bb.x, acc1 * inv + bb.y);
    }
}

extern "C" void kernel_launch(void* const* d_in, const int* in_sizes, int n_in,
                              void* d_out, int out_size, void* d_ws, size_t ws_size,
                              hipStream_t stream) {
    const float* x   = (const float*)d_in[0];
    const int*   ei  = (const int*)d_in[1];
    const float* W1  = (const float*)d_in[2];
    const float* as1 = (const float*)d_in[3];
    const float* ad1 = (const float*)d_in[4];
    const float* b1  = (const float*)d_in[5];
    const float* W2  = (const float*)d_in[6];
    const float* as2 = (const float*)d_in[7];
    const float* ad2 = (const float*)d_in[8];
    const float* b2  = (const float*)d_in[9];
    float* out = (float*)d_out;

    const int N   = in_sizes[0] / 128;
    const int E   = in_sizes[1] / 2;
    const int Et  = E + N;
    const int NBK = (N + 255) >> SHIFT;
    const int GBM = (N + 63) / 64;

    // ---- workspace layout ----
    char* p = (char*)d_ws;
    unsigned short* W1s = (unsigned short*)p; p += 32768 * 2;   // 64 KB
    unsigned short* W2s = (unsigned short*)p; p += 12288 * 2;   // 24 KB
    unsigned short* xhb = (unsigned short*)p; p += (size_t)N * 128 * 2;
    float* es1  = (float*)p; p += (size_t)N * 8 * 4;
    float* ed1  = (float*)p; p += (size_t)N * 8 * 4;
    int*   deg  = (int*)p;   p += (size_t)N * 4;
    int*   rowp = (int*)p;   p += (size_t)N * 4;
    int*   csr  = (int*)p;   p += (size_t)Et * 4;
    int*   H    = (int*)p;   p += (size_t)512 * ABLK * 4;
    int*   BT   = (int*)p;   p += 512 * 4;
    int*   BB   = (int*)p;   p += 512 * 4;
    unsigned short* hbuf = (unsigned short*)p; p += (size_t)N * 128 * 2;
    unsigned short* xh2  = (unsigned short*)p; p += (size_t)N * 64 * 2;
    unsigned* E2 = (unsigned*)hbuf;   // 6.8 MB < 25.6 MB; dead after k_bcsr
    float* es2 = es1;
    float* ed2 = ed1;

    k_prep  <<<88,              256, 0, stream>>>(W1, W2, W1s, W2s);
    k_mm1   <<<GBM,             256, 0, stream>>>(x, W1s, xhb, N);
    k_esed1 <<<(N * 8 + 255)/256, 256, 0, stream>>>(xhb, as1, ad1, es1, ed1, N);
    k_bhist <<<ABLK,            256, 0, stream>>>(ei, E, N, NBK, H);
    k_scanH <<<NBK,             512, 0, stream>>>(H, BT);
    k_scanBT<<<1,               512, 0, stream>>>(BT, BB, NBK);
    k_bscat <<<ABLK,            256, 0, stream>>>(ei, E, N, NBK, H, BB, E2);
    k_bcsr  <<<NBK,             256, 0, stream>>>(E2, BB, N, deg, rowp, csr);
    k_l1    <<<(N + 3) / 4,     256, 0, stream>>>(xhb, es1, ed1, rowp, deg, csr, b1, hbuf, N);
    k_mm2   <<<GBM,             256, 0, stream>>>(hbuf, W2s, xh2, N);
    k_esed2 <<<(N + 255) / 256, 256, 0, stream>>>(xh2, as2, ad2, es2, ed2, N);
    k_l2    <<<(N + 3) / 4,     256, 0, stream>>>(xh2, es2, ed2, rowp, deg, csr, b2, out, N);
}